// Round 1
// 413.604 us; speedup vs baseline: 1.0156x; 1.0156x over previous
//
#include <hip/hip_runtime.h>

// LinearAttentionBlock: B=8 T=512 FIN=256 D=128
// out   [B,T,D]    @ d_out + 0
// S_out [B,T,D*D]  @ d_out + 524288      (256 MiB -> HBM-write bound floor ~46us @5.9TB/s)
// Z     [B,T,D]    @ d_out + 524288 + 67108864

constexpr int BB = 8, TT = 512, FIN_ = 256, DD = 128;
constexpr int NROW = BB * TT;       // 4096
constexpr int CLEN = 64, NCH = 8;   // chunk length, chunks per batch (T = CLEN*NCH)
constexpr float CLAMPV = 1e20f;

typedef float f4v __attribute__((ext_vector_type(4)));

// ---------------- 1. LayerNorm: one wave per row, shuffle reduction, no barriers ----------------
__global__ __launch_bounds__(256) void ln_kernel(
    const float* __restrict__ x, const float* __restrict__ gamma,
    const float* __restrict__ beta, float* __restrict__ xn)
{
  int tid = threadIdx.x;
  int row = blockIdx.x * 4 + (tid >> 6);
  int lane = tid & 63;
  float4 v = *(const float4*)&x[row * FIN_ + lane * 4];
  float sum = v.x + v.y + v.z + v.w;
  float sq  = v.x * v.x + v.y * v.y + v.z * v.z + v.w * v.w;
#pragma unroll
  for (int off = 1; off < 64; off <<= 1) {
    sum += __shfl_xor(sum, off);
    sq  += __shfl_xor(sq, off);
  }
  float mu  = sum * (1.0f / FIN_);
  float var = sq * (1.0f / FIN_) - mu * mu;
  float rs  = rsqrtf(var + 1e-5f);
  float4 g = *(const float4*)&gamma[lane * 4];
  float4 b = *(const float4*)&beta[lane * 4];
  float4 o;
  o.x = (v.x - mu) * rs * g.x + b.x;
  o.y = (v.y - mu) * rs * g.y + b.y;
  o.z = (v.z - mu) * rs * g.z + b.z;
  o.w = (v.w - mu) * rs * g.w + b.w;
  *(float4*)&xn[row * FIN_ + lane * 4] = o;
}

// ---------------- 2. xn @ {Wk,Wq,Wv,Ws} fused GEMM, 64x64 tiles, 4x4 micro ----------------
__global__ __launch_bounds__(256) void gemm_qkvs(
    const float* __restrict__ xn,
    const float* __restrict__ Wk, const float* __restrict__ Wq,
    const float* __restrict__ Wv, const float* __restrict__ Ws,
    const float* __restrict__ bs,
    float* __restrict__ Kb, float* __restrict__ Qb,
    float* __restrict__ Vb, float* __restrict__ Rb)
{
  int ct = blockIdx.x, rt = blockIdx.y;
  int mat = ct >> 1, cb = (ct & 1) * 64;
  const float* W = (mat == 0) ? Wk : (mat == 1) ? Wq : (mat == 2) ? Wv : Ws;
  float* Ob      = (mat == 0) ? Kb : (mat == 1) ? Qb : (mat == 2) ? Vb : Rb;
  __shared__ float As[16][64];   // [k][m]
  __shared__ float Bs[16][64];   // [k][n]
  int tid = threadIdx.x;
  int tn = tid & 15, tm = tid >> 4;
  int lm = tid >> 2, lq = tid & 3;
  int lk = tid >> 4, ln4 = (tid & 15) * 4;
  float acc[4][4] = {};
  for (int k0 = 0; k0 < FIN_; k0 += 16) {
    float4 av = *(const float4*)&xn[(rt * 64 + lm) * FIN_ + k0 + lq * 4];
    As[lq * 4 + 0][lm] = av.x;
    As[lq * 4 + 1][lm] = av.y;
    As[lq * 4 + 2][lm] = av.z;
    As[lq * 4 + 3][lm] = av.w;
    *(float4*)&Bs[lk][ln4] = *(const float4*)&W[(k0 + lk) * DD + cb + ln4];
    __syncthreads();
#pragma unroll
    for (int k = 0; k < 16; k++) {
      float4 a = *(const float4*)&As[k][tm * 4];
      float4 b = *(const float4*)&Bs[k][tn * 4];
      float ar[4] = {a.x, a.y, a.z, a.w};
      float br[4] = {b.x, b.y, b.z, b.w};
#pragma unroll
      for (int i = 0; i < 4; i++)
#pragma unroll
        for (int j = 0; j < 4; j++) acc[i][j] += ar[i] * br[j];
    }
    __syncthreads();
  }
#pragma unroll
  for (int i = 0; i < 4; i++) {
    int row = rt * 64 + tm * 4 + i;
    int col = cb + tn * 4;
    float vals[4];
#pragma unroll
    for (int j = 0; j < 4; j++) {
      float v = acc[i][j];
      if (mat <= 1) v = (v > 0.f) ? v + 1.f : expf(v);   // phi = elu + 1
      else if (mat == 3) v += bs[col + j];
      vals[j] = v;
    }
    float4 o = make_float4(vals[0], vals[1], vals[2], vals[3]);
    *(float4*)&Ob[row * DD + col] = o;
  }
}

// ---------------- 3. per-chunk sums, split over j: grid (4 jt, NCH, BB) = 256 blocks ----------------
__global__ __launch_bounds__(256) void chunksum_kernel(
    const float* __restrict__ Kb, const float* __restrict__ Vb,
    float* __restrict__ chunkS, float* __restrict__ chunkz)
{
  int jt = blockIdx.x, c = blockIdx.y, b = blockIdx.z, tid = threadIdx.x;
  __shared__ float Ks[CLEN][DD];    // 32 KB
  __shared__ float Vs[CLEN][32];    // 8 KB
  const float* Kc = Kb + (b * TT + c * CLEN) * DD;
  const float* Vc = Vb + (b * TT + c * CLEN) * DD + jt * 32;
  for (int u = 0; u < 8; u++) {
    int idx = u * 256 + tid;
    int t = idx >> 5, c4 = (idx & 31) * 4;
    *(float4*)&Ks[t][c4] = *(const float4*)&Kc[t * DD + c4];
  }
  for (int u = 0; u < 2; u++) {
    int idx = u * 256 + tid;
    int t = idx >> 3, c4 = (idx & 7) * 4;
    *(float4*)&Vs[t][c4] = *(const float4*)&Vc[t * DD + c4];
  }
  __syncthreads();
  int ti = tid >> 3, tj = tid & 7;     // i0 = ti*4 (0..124), local j = tj*4
  int i0 = ti * 4, jl = tj * 4;
  float acc[4][4] = {};
  for (int t = 0; t < CLEN; t++) {
    float4 kv = *(const float4*)&Ks[t][i0];
    float4 vv = *(const float4*)&Vs[t][jl];
    float kr[4] = {kv.x, kv.y, kv.z, kv.w};
    float vr[4] = {vv.x, vv.y, vv.z, vv.w};
#pragma unroll
    for (int i = 0; i < 4; i++)
#pragma unroll
      for (int j = 0; j < 4; j++) acc[i][j] += kr[i] * vr[j];
  }
  float* oS = chunkS + (b * NCH + c) * DD * DD + jt * 32;
#pragma unroll
  for (int i = 0; i < 4; i++)
    *(float4*)&oS[(i0 + i) * DD + jl] = *(float4*)&acc[i][0];
  if (jt == 0 && tid < DD) {
    float z = 0.f;
    for (int t = 0; t < CLEN; t++) z += Ks[t][tid];
    chunkz[(b * NCH + c) * DD + tid] = z;
  }
}

// ---------------- 4. exclusive scans over chunks (S and Z merged, S0/Z0 folded in) ----------------
__global__ __launch_bounds__(256) void scan_kernel(
    const float* __restrict__ chunkS, const float* __restrict__ S0,
    float* __restrict__ prefS,
    const float* __restrict__ chunkz, const float* __restrict__ Z0,
    float* __restrict__ prefz)
{
  int b = blockIdx.y;
  if (blockIdx.x == 64) {                     // z-scan block
    int i = threadIdx.x;
    if (i < DD) {
      float z0v = Z0[b * DD + i];
      float acc = 0.f;
      for (int c = 0; c < NCH; c++) {
        prefz[(b * NCH + c) * DD + i] = acc + z0v;
        acc += chunkz[(b * NCH + c) * DD + i];
      }
    }
    return;
  }
  int idx = blockIdx.x * 256 + threadIdx.x;   // 0..16383
  float s0v = S0[b * DD * DD + idx];
  float acc = 0.f;
  for (int c = 0; c < NCH; c++) {
    prefS[(b * NCH + c) * DD * DD + idx] = acc + s0v;
    acc += chunkS[(b * NCH + c) * DD * DD + idx];
  }
}

// ---------------- 5. S streaming: grid (16 it, NCH, BB) = 1024 blocks, 4/CU ----------------
// block owns state rows i0..i0+7, all 128 cols. Nontemporal stores: S_out is
// write-once (268 MB) — keep it out of L2/LLC so prefS/K/V stay resident.
__global__ __launch_bounds__(256) void s_write_kernel(
    const float* __restrict__ Kb, const float* __restrict__ Vb,
    const float* __restrict__ prefS, float* __restrict__ Sout)
{
  int it = blockIdx.x, c = blockIdx.y, b = blockIdx.z;
  int i0 = it * 8;
  __shared__ float Vs[CLEN][DD];    // 32 KB
  __shared__ float Ksm[CLEN][8];    // 2 KB
  int tid = threadIdx.x;
  const float* Kc = Kb + (b * TT + c * CLEN) * DD;
  const float* Vc = Vb + (b * TT + c * CLEN) * DD;
  for (int u = 0; u < 8; u++) {
    int idx = u * 256 + tid;
    int t = idx >> 5, c4 = (idx & 31) * 4;
    *(float4*)&Vs[t][c4] = *(const float4*)&Vc[t * DD + c4];
  }
  for (int u = 0; u < 2; u++) {
    int idx = u * 256 + tid;
    int t = idx >> 3, r = idx & 7;
    Ksm[t][r] = Kc[t * DD + i0 + r];
  }
  __syncthreads();
  int irow = tid >> 5, jq = tid & 31;
  int j = jq * 4;
  float4 pref = *(const float4*)&prefS[(b * NCH + c) * DD * DD + (i0 + irow) * DD + j];
  float4 acc = make_float4(0.f, 0.f, 0.f, 0.f);
  float* So = Sout + (size_t)(b * TT + c * CLEN) * (DD * DD) + (i0 + irow) * DD + j;
#pragma unroll 4
  for (int t = 0; t < CLEN; t++) {
    float4 v4 = *(const float4*)&Vs[t][j];
    float kk = Ksm[t][irow];
    acc.x += kk * v4.x; acc.y += kk * v4.y;
    acc.z += kk * v4.z; acc.w += kk * v4.w;
    f4v o4;
    o4.x = fminf(fmaxf(pref.x + acc.x, -CLAMPV), CLAMPV);
    o4.y = fminf(fmaxf(pref.y + acc.y, -CLAMPV), CLAMPV);
    o4.z = fminf(fmaxf(pref.z + acc.z, -CLAMPV), CLAMPV);
    o4.w = fminf(fmaxf(pref.w + acc.w, -CLAMPV), CLAMPV);
    __builtin_nontemporal_store(o4, (f4v*)&So[(size_t)t * (DD * DD)]);
  }
}

// ---------------- 6. fused attention, v3: grid (4 sub, NCH, BB) = 256 blocks ----------------
// each block owns 16 t-rows of one chunk; K staged only up to causal limit tlim.
// Z cumsum handled by the sub==3 block (has full K in LDS). 45 KB LDS -> all CUs busy.
__global__ __launch_bounds__(256) void attn_kernel(
    const float* __restrict__ Kb, const float* __restrict__ Qb,
    const float* __restrict__ Vb, const float* __restrict__ prefS,
    const float* __restrict__ prefz,
    float* __restrict__ Zout, float* __restrict__ attn_o)
{
  int sub = blockIdx.x, c = blockIdx.y, b = blockIdx.z, tid = threadIdx.x;
  int t0 = sub * 16;
  int tlim = t0 + 16;                    // taus needed: 0..tlim-1
  __shared__ float KsT[DD][CLEN + 1];    // [k][tau]  33.3 KB (only cols < tlim valid)
  __shared__ float Qs[16][DD + 1];       // [r][k]    8.25 KB
  __shared__ float sc[16][CLEN + 1];     //           4.2 KB
  __shared__ float zeff[DD];
  __shared__ float den[16];
  const float* Kc = Kb + (b * TT + c * CLEN) * DD;
  const float* Qc = Qb + (b * TT + c * CLEN) * DD;
  const float* Vc = Vb + (b * TT + c * CLEN) * DD;
  // stage K^T (causal-trimmed) and Q rows t0..t0+15
  for (int idx = tid; idx < tlim * 32; idx += 256) {
    int t = idx >> 5, c4 = (idx & 31) * 4;
    float4 v = *(const float4*)&Kc[t * DD + c4];
    KsT[c4 + 0][t] = v.x; KsT[c4 + 1][t] = v.y;
    KsT[c4 + 2][t] = v.z; KsT[c4 + 3][t] = v.w;
  }
  for (int idx = tid; idx < 16 * 32; idx += 256) {
    int r = idx >> 5, c4 = (idx & 31) * 4;
    float4 q = *(const float4*)&Qc[(t0 + r) * DD + c4];
    Qs[r][c4 + 0] = q.x; Qs[r][c4 + 1] = q.y;
    Qs[r][c4 + 2] = q.z; Qs[r][c4 + 3] = q.w;
  }
  if (tid < DD) zeff[tid] = prefz[(b * NCH + c) * DD + tid];
  __syncthreads();
  // scores: tril(Q K^T) for rows t0..t0+15
  {
    int tm = tid >> 4, tn = tid & 15;    // row r=tm, taus tn*4..tn*4+3
    if (tn * 4 < tlim) {
      float s0 = 0.f, s1 = 0.f, s2 = 0.f, s3 = 0.f;
#pragma unroll 4
      for (int k = 0; k < DD; k++) {
        float q = Qs[tm][k];
        s0 += q * KsT[k][tn * 4 + 0];
        s1 += q * KsT[k][tn * 4 + 1];
        s2 += q * KsT[k][tn * 4 + 2];
        s3 += q * KsT[k][tn * 4 + 3];
      }
      int t = t0 + tm;
      sc[tm][tn * 4 + 0] = (tn * 4 + 0 <= t) ? s0 : 0.f;
      sc[tm][tn * 4 + 1] = (tn * 4 + 1 <= t) ? s1 : 0.f;
      sc[tm][tn * 4 + 2] = (tn * 4 + 2 <= t) ? s2 : 0.f;
      sc[tm][tn * 4 + 3] = (tn * 4 + 3 <= t) ? s3 : 0.f;
    }
  }
  __syncthreads();
  if (tid < 16) {
    int t = t0 + tid;
    float d = 0.f;
    for (int tau = 0; tau <= t; tau++) d += sc[tid][tau];
    float dz = 0.f;
    for (int k = 0; k < DD; k++) dz += Qs[tid][k] * zeff[k];
    den[tid] = d + dz + 1e-5f;
  }
  __syncthreads();
  // numerator: rows 2*tg, 2*tg+1; cols l0..l0+3
  int tl = tid & 31, tg = tid >> 5;
  int l0 = tl * 4, r0 = tg * 2, r1 = tg * 2 + 1;
  float n0[4] = {}, n1[4] = {};
  for (int tau = 0; tau < tlim; tau++) {
    float4 v4 = *(const float4*)&Vc[tau * DD + l0];
    float sa = sc[r0][tau], sb = sc[r1][tau];
    n0[0] += sa * v4.x; n0[1] += sa * v4.y; n0[2] += sa * v4.z; n0[3] += sa * v4.w;
    n1[0] += sb * v4.x; n1[1] += sb * v4.y; n1[2] += sb * v4.z; n1[3] += sb * v4.w;
  }
  const float* P = prefS + (b * NCH + c) * DD * DD;
#pragma unroll 2
  for (int i = 0; i < DD; i++) {
    float4 p4 = *(const float4*)&P[i * DD + l0];
    float qa = Qs[r0][i], qb = Qs[r1][i];
    n0[0] += qa * p4.x; n0[1] += qa * p4.y; n0[2] += qa * p4.z; n0[3] += qa * p4.w;
    n1[0] += qb * p4.x; n1[1] += qb * p4.y; n1[2] += qb * p4.z; n1[3] += qb * p4.w;
  }
  float* og = attn_o + (size_t)(b * TT + c * CLEN + t0) * DD;
  {
    float da = den[r0], db = den[r1];
    float4 oa = make_float4(n0[0] / da, n0[1] / da, n0[2] / da, n0[3] / da);
    float4 ob = make_float4(n1[0] / db, n1[1] / db, n1[2] / db, n1[3] / db);
    *(float4*)&og[r0 * DD + l0] = oa;
    *(float4*)&og[r1 * DD + l0] = ob;
  }
  // Z output: sub==3 block has the full K chunk staged
  if (sub == 3 && tid < DD) {
    int i = tid;
    float a = zeff[i];
    for (int t = 0; t < CLEN; t++) {
      a += KsT[i][t];
      a = fminf(fmaxf(a, -CLAMPV), CLAMPV);
      __builtin_nontemporal_store(a, &Zout[(size_t)(b * TT + c * CLEN + t) * DD + i]);
    }
  }
}

// ---------------- 7. FFN + residual: 256 blocks x 128 threads (16-row tiles) ----------------
__global__ __launch_bounds__(128) void ffn_kernel(
    const float* __restrict__ att, const float* __restrict__ res,
    const float* __restrict__ W1, const float* __restrict__ b1,
    const float* __restrict__ W2, const float* __restrict__ b2,
    float* __restrict__ outp)
{
  int rt = blockIdx.x, tid = threadIdx.x;
  __shared__ float As[16][129];
  __shared__ float H1[16][129];
  const float* ab = att + rt * 16 * DD;
  for (int u = 0; u < 4; u++) {
    int idx = u * 128 + tid;             // 512 float4s = 16 rows x 32
    int r = idx >> 5, c4 = (idx & 31) * 4;
    float4 v = *(const float4*)&ab[r * DD + c4];
    As[r][c4 + 0] = v.x; As[r][c4 + 1] = v.y;
    As[r][c4 + 2] = v.z; As[r][c4 + 3] = v.w;
  }
  __syncthreads();
  int cn = tid & 31, rm = tid >> 5;      // rm 0..3 -> rows rm*4..rm*4+3
  int col = cn * 4, r0 = rm * 4;
  float acc[4][4] = {};
  for (int k = 0; k < DD; k++) {
    float4 w = *(const float4*)&W1[k * DD + col];
    float a[4];
#pragma unroll
    for (int i = 0; i < 4; i++) a[i] = As[r0 + i][k];
#pragma unroll
    for (int i = 0; i < 4; i++) {
      acc[i][0] += a[i] * w.x; acc[i][1] += a[i] * w.y;
      acc[i][2] += a[i] * w.z; acc[i][3] += a[i] * w.w;
    }
  }
  float4 bv = *(const float4*)&b1[col];
#pragma unroll
  for (int i = 0; i < 4; i++) {
    H1[r0 + i][col + 0] = fmaxf(acc[i][0] + bv.x, 0.f);
    H1[r0 + i][col + 1] = fmaxf(acc[i][1] + bv.y, 0.f);
    H1[r0 + i][col + 2] = fmaxf(acc[i][2] + bv.z, 0.f);
    H1[r0 + i][col + 3] = fmaxf(acc[i][3] + bv.w, 0.f);
  }
  __syncthreads();
  float acc2[4][4] = {};
  for (int k = 0; k < DD; k++) {
    float4 w = *(const float4*)&W2[k * DD + col];
    float a[4];
#pragma unroll
    for (int i = 0; i < 4; i++) a[i] = H1[r0 + i][k];
#pragma unroll
    for (int i = 0; i < 4; i++) {
      acc2[i][0] += a[i] * w.x; acc2[i][1] += a[i] * w.y;
      acc2[i][2] += a[i] * w.z; acc2[i][3] += a[i] * w.w;
    }
  }
  float4 b2v = *(const float4*)&b2[col];
#pragma unroll
  for (int i = 0; i < 4; i++) {
    int row = rt * 16 + r0 + i;
    float4 rv = *(const float4*)&res[row * DD + col];
    float4 o;
    o.x = fmaxf(acc2[i][0] + b2v.x, 0.f) + rv.x;
    o.y = fmaxf(acc2[i][1] + b2v.y, 0.f) + rv.y;
    o.z = fmaxf(acc2[i][2] + b2v.z, 0.f) + rv.z;
    o.w = fmaxf(acc2[i][3] + b2v.w, 0.f) + rv.w;
    *(float4*)&outp[row * DD + col] = o;
  }
}

extern "C" void kernel_launch(void* const* d_in, const int* in_sizes, int n_in,
                              void* d_out, int out_size, void* d_ws, size_t ws_size,
                              hipStream_t stream)
{
  const float* x     = (const float*)d_in[0];
  const float* S0    = (const float*)d_in[1];
  const float* Z0    = (const float*)d_in[2];
  const float* gamma = (const float*)d_in[3];
  const float* beta  = (const float*)d_in[4];
  const float* Wk    = (const float*)d_in[5];
  const float* Wq    = (const float*)d_in[6];
  const float* Wv    = (const float*)d_in[7];
  const float* W1    = (const float*)d_in[8];
  const float* b1    = (const float*)d_in[9];
  const float* W2    = (const float*)d_in[10];
  const float* b2    = (const float*)d_in[11];
  const float* Ws    = (const float*)d_in[12];
  const float* bs    = (const float*)d_in[13];

  float* out_main = (float*)d_out;                       // [B,T,D]
  float* Sout = out_main + NROW * DD;                    // [B,T,D*D]
  float* Zout = Sout + (size_t)NROW * DD * DD;           // [B,T,D]

  float* ws_f   = (float*)d_ws;
  float* xn     = ws_f;                  // 1048576
  float* Kb     = xn + 1048576;          // 524288
  float* Qb     = Kb + 524288;           // 524288
  float* Vb     = Qb + 524288;           // 524288
  float* Rb     = Vb + 524288;           // 524288  (xn@Ws + bs)
  float* chunkS = Rb + 524288;           // 1048576
  float* prefS  = chunkS + 1048576;      // 1048576 (exclusive prefix + S0)
  float* chunkz = prefS + 1048576;       // 8192
  float* prefz  = chunkz + 8192;         // 8192    (exclusive prefix + Z0)
  float* attn_o = prefz + 8192;          // 524288

  ln_kernel<<<NROW / 4, 256, 0, stream>>>(x, gamma, beta, xn);
  gemm_qkvs<<<dim3(8, 64), 256, 0, stream>>>(xn, Wk, Wq, Wv, Ws, bs, Kb, Qb, Vb, Rb);
  chunksum_kernel<<<dim3(4, NCH, BB), 256, 0, stream>>>(Kb, Vb, chunkS, chunkz);
  scan_kernel<<<dim3(65, BB), 256, 0, stream>>>(chunkS, S0, prefS, chunkz, Z0, prefz);
  s_write_kernel<<<dim3(16, NCH, BB), 256, 0, stream>>>(Kb, Vb, prefS, Sout);
  attn_kernel<<<dim3(4, NCH, BB), 256, 0, stream>>>(Kb, Qb, Vb, prefS, prefz, Zout, attn_o);
  ffn_kernel<<<NROW / 16, 128, 0, stream>>>(attn_o, Rb, W1, b1, W2, b2, out_main);
}

// Round 2
// 402.178 us; speedup vs baseline: 1.0444x; 1.0284x over previous
//
#include <hip/hip_runtime.h>

// LinearAttentionBlock: B=8 T=512 FIN=256 D=128
// out   [B,T,D]    @ d_out + 0
// S_out [B,T,D*D]  @ d_out + 524288      (256 MiB -> HBM-write bound floor ~46us)
// Z     [B,T,D]    @ d_out + 524288 + 67108864

constexpr int BB = 8, TT = 512, FIN_ = 256, DD = 128;
constexpr int NROW = BB * TT;       // 4096
constexpr int CLEN = 64, NCH = 8;   // chunk length, chunks per batch (T = CLEN*NCH)
constexpr float CLAMPV = 1e20f;

typedef float f4v __attribute__((ext_vector_type(4)));

// ---------------- 1. LN fused into xn @ {Wk,Wq,Wv,Ws} GEMM, 64x64 tiles, 4x4 micro ----------------
// Each block recomputes LN stats for its 64 rows (redundant across 8 column-tiles; x rows are
// L1/L2-hot). Kills the separate ln kernel + xn round-trip.
__global__ __launch_bounds__(256) void gemm_qkvs(
    const float* __restrict__ x,
    const float* __restrict__ gamma, const float* __restrict__ beta,
    const float* __restrict__ Wk, const float* __restrict__ Wq,
    const float* __restrict__ Wv, const float* __restrict__ Ws,
    const float* __restrict__ bs,
    float* __restrict__ Kb, float* __restrict__ Qb,
    float* __restrict__ Vb, float* __restrict__ Rb)
{
  int ct = blockIdx.x, rt = blockIdx.y;
  int mat = ct >> 1, cb = (ct & 1) * 64;
  const float* W = (mat == 0) ? Wk : (mat == 1) ? Wq : (mat == 2) ? Wv : Ws;
  float* Ob      = (mat == 0) ? Kb : (mat == 1) ? Qb : (mat == 2) ? Vb : Rb;
  __shared__ float As[16][64];   // [k][m]
  __shared__ float Bs[16][64];   // [k][n]
  __shared__ float mu_s[64], rs_s[64];
  int tid = threadIdx.x;
  // ---- LN stats: 4 lanes per row (row = tid>>2, quarter = tid&3) ----
  {
    int row = tid >> 2, q = tid & 3;
    const float* xr = &x[(rt * 64 + row) * FIN_ + q * 64];
    float sum = 0.f, sq = 0.f;
#pragma unroll
    for (int u = 0; u < 16; u++) {
      float4 v = *(const float4*)&xr[u * 4];
      sum += v.x + v.y + v.z + v.w;
      sq  += v.x * v.x + v.y * v.y + v.z * v.z + v.w * v.w;
    }
    sum += __shfl_xor(sum, 1); sq += __shfl_xor(sq, 1);
    sum += __shfl_xor(sum, 2); sq += __shfl_xor(sq, 2);
    if (q == 0) {
      float mu = sum * (1.0f / FIN_);
      float var = sq * (1.0f / FIN_) - mu * mu;
      mu_s[row] = mu;
      rs_s[row] = rsqrtf(var + 1e-5f);
    }
  }
  __syncthreads();
  int tn = tid & 15, tm = tid >> 4;
  int lm = tid >> 2, lq = tid & 3;
  int lk = tid >> 4, ln4 = (tid & 15) * 4;
  float acc[4][4] = {};
  float mu = mu_s[lm], rs = rs_s[lm];
  for (int k0 = 0; k0 < FIN_; k0 += 16) {
    float4 av = *(const float4*)&x[(rt * 64 + lm) * FIN_ + k0 + lq * 4];
    float4 g  = *(const float4*)&gamma[k0 + lq * 4];
    float4 be = *(const float4*)&beta[k0 + lq * 4];
    As[lq * 4 + 0][lm] = (av.x - mu) * rs * g.x + be.x;
    As[lq * 4 + 1][lm] = (av.y - mu) * rs * g.y + be.y;
    As[lq * 4 + 2][lm] = (av.z - mu) * rs * g.z + be.z;
    As[lq * 4 + 3][lm] = (av.w - mu) * rs * g.w + be.w;
    *(float4*)&Bs[lk][ln4] = *(const float4*)&W[(k0 + lk) * DD + cb + ln4];
    __syncthreads();
#pragma unroll
    for (int k = 0; k < 16; k++) {
      float4 a = *(const float4*)&As[k][tm * 4];
      float4 b = *(const float4*)&Bs[k][tn * 4];
      float ar[4] = {a.x, a.y, a.z, a.w};
      float br[4] = {b.x, b.y, b.z, b.w};
#pragma unroll
      for (int i = 0; i < 4; i++)
#pragma unroll
        for (int j = 0; j < 4; j++) acc[i][j] += ar[i] * br[j];
    }
    __syncthreads();
  }
#pragma unroll
  for (int i = 0; i < 4; i++) {
    int row = rt * 64 + tm * 4 + i;
    int col = cb + tn * 4;
    float vals[4];
#pragma unroll
    for (int j = 0; j < 4; j++) {
      float v = acc[i][j];
      if (mat <= 1) v = (v > 0.f) ? v + 1.f : expf(v);   // phi = elu + 1
      else if (mat == 3) v += bs[col + j];
      vals[j] = v;
    }
    float4 o = make_float4(vals[0], vals[1], vals[2], vals[3]);
    *(float4*)&Ob[row * DD + col] = o;
  }
}

// ---------------- 2. chunk sums + exclusive scan fused: grid (4 jt, 8 it, BB) = 256 blocks ----------
// Block owns S-tile [16 i][32 j] of one batch; iterates the 8 chunks sequentially, writing the
// exclusive prefix (+S0) before accumulating each chunk. Same summation order as before.
// Kills the chunkS round-trip (8.4 MB) and one launch. jt==0 blocks also produce prefz.
__global__ __launch_bounds__(256) void prefix_kernel(
    const float* __restrict__ Kb, const float* __restrict__ Vb,
    const float* __restrict__ S0, const float* __restrict__ Z0,
    float* __restrict__ prefS, float* __restrict__ prefz)
{
  int jt = blockIdx.x, it = blockIdx.y, b = blockIdx.z;
  int i0 = it * 16, j0 = jt * 32;
  __shared__ float Ks[CLEN][16];   // 4 KB
  __shared__ float Vs[CLEN][32];   // 8 KB
  int tid = threadIdx.x;
  int il = tid >> 4, jl = tid & 15;          // i = i0+il, cols j0+jl*2, +1
  float2 s0v = *(const float2*)&S0[b * DD * DD + (i0 + il) * DD + j0 + jl * 2];
  float acc0 = 0.f, acc1 = 0.f;
  float zacc = 0.f;
  float z0v = (jt == 0 && tid < 16) ? Z0[b * DD + i0 + tid] : 0.f;
  for (int c = 0; c < NCH; c++) {
    const float* Kc = Kb + (b * TT + c * CLEN) * DD;
    const float* Vc = Vb + (b * TT + c * CLEN) * DD;
    {
      int t = tid >> 2, i4 = (tid & 3) * 4;
      *(float4*)&Ks[t][i4] = *(const float4*)&Kc[t * DD + i0 + i4];
    }
#pragma unroll
    for (int u = 0; u < 2; u++) {
      int idx = u * 256 + tid;
      int t = idx >> 3, j4 = (idx & 7) * 4;
      *(float4*)&Vs[t][j4] = *(const float4*)&Vc[t * DD + j0 + j4];
    }
    __syncthreads();
    // exclusive prefix out
    float2 op = make_float2(acc0 + s0v.x, acc1 + s0v.y);
    *(float2*)&prefS[(size_t)(b * NCH + c) * DD * DD + (i0 + il) * DD + j0 + jl * 2] = op;
    if (jt == 0 && tid < 16)
      prefz[(b * NCH + c) * DD + i0 + tid] = zacc + z0v;
    // accumulate this chunk
#pragma unroll 8
    for (int t = 0; t < CLEN; t++) {
      float k = Ks[t][il];
      float2 v2 = *(const float2*)&Vs[t][jl * 2];
      acc0 += k * v2.x;
      acc1 += k * v2.y;
    }
    if (jt == 0 && tid < 16) {
      float z = 0.f;
#pragma unroll 8
      for (int t = 0; t < CLEN; t++) z += Ks[t][tid];
      zacc += z;
    }
    __syncthreads();
  }
}

// ---------------- 3. fused attention: grid (8 sub, NCH, BB) = 512 blocks, 2/CU ----------------
// Each block owns 8 t-rows; K^T staged causal-trimmed; KsT padded to 66 so score reads are
// aligned ds_read_b64. Z cumsum done by sub==7 (full K staged).
__global__ __launch_bounds__(256) void attn_kernel(
    const float* __restrict__ Kb, const float* __restrict__ Qb,
    const float* __restrict__ Vb, const float* __restrict__ prefS,
    const float* __restrict__ prefz,
    float* __restrict__ Zout, float* __restrict__ attn_o)
{
  int sub = blockIdx.x, c = blockIdx.y, b = blockIdx.z, tid = threadIdx.x;
  int t0 = sub * 8;
  int tlim = t0 + 8;                     // taus needed: 0..tlim-1
  __shared__ float KsT[DD][CLEN + 2];    // [k][tau] 33.8 KB, pad 66 keeps 8B align for float2
  __shared__ float Qs[8][132];           // 4.2 KB (stride 132 -> 16B-aligned float4 rows)
  __shared__ float sc[8][CLEN + 2];      // 2.1 KB
  __shared__ float zeff[DD];
  __shared__ float den[8];
  const float* Kc = Kb + (b * TT + c * CLEN) * DD;
  const float* Qc = Qb + (b * TT + c * CLEN) * DD;
  const float* Vc = Vb + (b * TT + c * CLEN) * DD;
  for (int idx = tid; idx < tlim * 32; idx += 256) {
    int t = idx >> 5, c4 = (idx & 31) * 4;
    float4 v = *(const float4*)&Kc[t * DD + c4];
    KsT[c4 + 0][t] = v.x; KsT[c4 + 1][t] = v.y;
    KsT[c4 + 2][t] = v.z; KsT[c4 + 3][t] = v.w;
  }
  {
    int r = tid >> 5, c4 = (tid & 31) * 4;
    float4 q = *(const float4*)&Qc[(t0 + r) * DD + c4];
    *(float4*)&Qs[r][c4] = q;
  }
  if (tid < DD) zeff[tid] = prefz[(b * NCH + c) * DD + tid];
  __syncthreads();
  // scores: row tm = tid>>5 (0..7), taus {2*tn, 2*tn+1}
  {
    int tm = tid >> 5, tn = tid & 31;
    int tau0 = tn * 2;
    if (tau0 < tlim) {
      float s0 = 0.f, s1 = 0.f;
#pragma unroll 8
      for (int k = 0; k < DD; k++) {
        float q = Qs[tm][k];
        float2 kk = *(const float2*)&KsT[k][tau0];
        s0 += q * kk.x;
        s1 += q * kk.y;
      }
      int t = t0 + tm;
      sc[tm][tau0]     = (tau0     <= t) ? s0 : 0.f;
      sc[tm][tau0 + 1] = (tau0 + 1 <= t) ? s1 : 0.f;
    }
  }
  __syncthreads();
  if (tid < 8) {
    int t = t0 + tid;
    float d = 0.f;
    for (int tau = 0; tau <= t; tau++) d += sc[tid][tau];
    float dz = 0.f;
#pragma unroll 8
    for (int k = 0; k < DD; k++) dz += Qs[tid][k] * zeff[k];
    den[tid] = d + dz + 1e-5f;
  }
  __syncthreads();
  // numerator: row r = tid>>5, cols l0..l0+3
  int tl = tid & 31, r = tid >> 5;
  int l0 = tl * 4;
  float n0[4] = {};
#pragma unroll 4
  for (int tau = 0; tau < tlim; tau++) {
    float4 v4 = *(const float4*)&Vc[tau * DD + l0];
    float s = sc[r][tau];
    n0[0] += s * v4.x; n0[1] += s * v4.y; n0[2] += s * v4.z; n0[3] += s * v4.w;
  }
  const float* P = prefS + (size_t)(b * NCH + c) * DD * DD;
#pragma unroll 4
  for (int i = 0; i < DD; i++) {
    float4 p4 = *(const float4*)&P[i * DD + l0];
    float q = Qs[r][i];
    n0[0] += q * p4.x; n0[1] += q * p4.y; n0[2] += q * p4.z; n0[3] += q * p4.w;
  }
  float* og = attn_o + (size_t)(b * TT + c * CLEN + t0) * DD;
  {
    float dd = den[r];
    float4 o = make_float4(n0[0] / dd, n0[1] / dd, n0[2] / dd, n0[3] / dd);
    *(float4*)&og[r * DD + l0] = o;
  }
  // Z output: sub==7 block has the full K chunk staged
  if (sub == 7 && tid < DD) {
    int i = tid;
    float a = zeff[i];
    for (int t = 0; t < CLEN; t++) {
      a += KsT[i][t];
      a = fminf(fmaxf(a, -CLAMPV), CLAMPV);
      __builtin_nontemporal_store(a, &Zout[(size_t)(b * TT + c * CLEN + t) * DD + i]);
    }
  }
}

// ---------------- 4. FFN + residual: 256 blocks x 256 threads, 16-row tiles ----------------
__global__ __launch_bounds__(256) void ffn_kernel(
    const float* __restrict__ att, const float* __restrict__ res,
    const float* __restrict__ W1, const float* __restrict__ b1,
    const float* __restrict__ W2, const float* __restrict__ b2,
    float* __restrict__ outp)
{
  int rt = blockIdx.x, tid = threadIdx.x;
  __shared__ float As[16][132];
  __shared__ float H1[16][132];
  const float* ab = att + rt * 16 * DD;
  {
    int idx = tid;                       // 512 float4s over 2 passes
#pragma unroll
    for (int u = 0; u < 2; u++, idx += 256) {
      int r = idx >> 5, c4 = (idx & 31) * 4;
      *(float4*)&As[r][c4] = *(const float4*)&ab[r * DD + c4];
    }
  }
  __syncthreads();
  int cn = tid & 31, rm = tid >> 5;      // rm 0..7 -> rows rm*2, rm*2+1
  int col = cn * 4, r0 = rm * 2;
  float acc[2][4] = {};
#pragma unroll 8
  for (int k = 0; k < DD; k++) {
    float4 w = *(const float4*)&W1[k * DD + col];
    float a0 = As[r0][k], a1 = As[r0 + 1][k];
    acc[0][0] += a0 * w.x; acc[0][1] += a0 * w.y; acc[0][2] += a0 * w.z; acc[0][3] += a0 * w.w;
    acc[1][0] += a1 * w.x; acc[1][1] += a1 * w.y; acc[1][2] += a1 * w.z; acc[1][3] += a1 * w.w;
  }
  float4 bv = *(const float4*)&b1[col];
#pragma unroll
  for (int i = 0; i < 2; i++) {
    float4 h;
    h.x = fmaxf(acc[i][0] + bv.x, 0.f);
    h.y = fmaxf(acc[i][1] + bv.y, 0.f);
    h.z = fmaxf(acc[i][2] + bv.z, 0.f);
    h.w = fmaxf(acc[i][3] + bv.w, 0.f);
    *(float4*)&H1[r0 + i][col] = h;
  }
  __syncthreads();
  float acc2[2][4] = {};
#pragma unroll 8
  for (int k = 0; k < DD; k++) {
    float4 w = *(const float4*)&W2[k * DD + col];
    float a0 = H1[r0][k], a1 = H1[r0 + 1][k];
    acc2[0][0] += a0 * w.x; acc2[0][1] += a0 * w.y; acc2[0][2] += a0 * w.z; acc2[0][3] += a0 * w.w;
    acc2[1][0] += a1 * w.x; acc2[1][1] += a1 * w.y; acc2[1][2] += a1 * w.z; acc2[1][3] += a1 * w.w;
  }
  float4 b2v = *(const float4*)&b2[col];
#pragma unroll
  for (int i = 0; i < 2; i++) {
    int row = rt * 16 + r0 + i;
    float4 rv = *(const float4*)&res[row * DD + col];
    float4 o;
    o.x = fmaxf(acc2[i][0] + b2v.x, 0.f) + rv.x;
    o.y = fmaxf(acc2[i][1] + b2v.y, 0.f) + rv.y;
    o.z = fmaxf(acc2[i][2] + b2v.z, 0.f) + rv.z;
    o.w = fmaxf(acc2[i][3] + b2v.w, 0.f) + rv.w;
    *(float4*)&outp[row * DD + col] = o;
  }
}

// ---------------- 5. S streaming: grid (8 it, NCH, BB) = 512 blocks x 512 thr, 2/CU ----------------
// Block owns 16 state rows, all 128 cols; V staged 8x (was 16x). Nontemporal stores keep the
// 268 MB write-once stream out of L2/LLC.
__global__ __launch_bounds__(512) void s_write_kernel(
    const float* __restrict__ Kb, const float* __restrict__ Vb,
    const float* __restrict__ prefS, float* __restrict__ Sout)
{
  int it = blockIdx.x, c = blockIdx.y, b = blockIdx.z;
  int i0 = it * 16;
  __shared__ float Vs[CLEN][DD];    // 32 KB
  __shared__ float Ksm[CLEN][16];   // 4 KB
  int tid = threadIdx.x;
  const float* Kc = Kb + (b * TT + c * CLEN) * DD;
  const float* Vc = Vb + (b * TT + c * CLEN) * DD;
#pragma unroll
  for (int u = 0; u < 4; u++) {
    int idx = u * 512 + tid;
    int t = idx >> 5, c4 = (idx & 31) * 4;
    *(float4*)&Vs[t][c4] = *(const float4*)&Vc[t * DD + c4];
  }
#pragma unroll
  for (int u = 0; u < 2; u++) {
    int idx = u * 512 + tid;
    int t = idx >> 4, r = idx & 15;
    Ksm[t][r] = Kc[t * DD + i0 + r];
  }
  __syncthreads();
  int irow = tid >> 5, jq = tid & 31;   // irow 0..15
  int j = jq * 4;
  float4 pref = *(const float4*)&prefS[(size_t)(b * NCH + c) * DD * DD + (i0 + irow) * DD + j];
  float4 acc = make_float4(0.f, 0.f, 0.f, 0.f);
  float* So = Sout + (size_t)(b * TT + c * CLEN) * (DD * DD) + (i0 + irow) * DD + j;
#pragma unroll 4
  for (int t = 0; t < CLEN; t++) {
    float4 v4 = *(const float4*)&Vs[t][j];
    float kk = Ksm[t][irow];
    acc.x += kk * v4.x; acc.y += kk * v4.y;
    acc.z += kk * v4.z; acc.w += kk * v4.w;
    f4v o4;
    o4.x = fminf(fmaxf(pref.x + acc.x, -CLAMPV), CLAMPV);
    o4.y = fminf(fmaxf(pref.y + acc.y, -CLAMPV), CLAMPV);
    o4.z = fminf(fmaxf(pref.z + acc.z, -CLAMPV), CLAMPV);
    o4.w = fminf(fmaxf(pref.w + acc.w, -CLAMPV), CLAMPV);
    __builtin_nontemporal_store(o4, (f4v*)&So[(size_t)t * (DD * DD)]);
  }
}

extern "C" void kernel_launch(void* const* d_in, const int* in_sizes, int n_in,
                              void* d_out, int out_size, void* d_ws, size_t ws_size,
                              hipStream_t stream)
{
  const float* x     = (const float*)d_in[0];
  const float* S0    = (const float*)d_in[1];
  const float* Z0    = (const float*)d_in[2];
  const float* gamma = (const float*)d_in[3];
  const float* beta  = (const float*)d_in[4];
  const float* Wk    = (const float*)d_in[5];
  const float* Wq    = (const float*)d_in[6];
  const float* Wv    = (const float*)d_in[7];
  const float* W1    = (const float*)d_in[8];
  const float* b1    = (const float*)d_in[9];
  const float* W2    = (const float*)d_in[10];
  const float* b2    = (const float*)d_in[11];
  const float* Ws    = (const float*)d_in[12];
  const float* bs    = (const float*)d_in[13];

  float* out_main = (float*)d_out;                       // [B,T,D]
  float* Sout = out_main + NROW * DD;                    // [B,T,D*D]
  float* Zout = Sout + (size_t)NROW * DD * DD;           // [B,T,D]

  float* ws_f   = (float*)d_ws;
  float* Kb     = ws_f;                  // 524288
  float* Qb     = Kb + 524288;           // 524288
  float* Vb     = Qb + 524288;           // 524288
  float* Rb     = Vb + 524288;           // 524288  (xn@Ws + bs)
  float* prefS  = Rb + 524288;           // 1048576 (exclusive prefix + S0)
  float* prefz  = prefS + 1048576;       // 8192    (exclusive prefix + Z0)
  float* attn_o = prefz + 8192;          // 524288

  gemm_qkvs<<<dim3(8, 64), 256, 0, stream>>>(x, gamma, beta, Wk, Wq, Wv, Ws, bs,
                                             Kb, Qb, Vb, Rb);
  prefix_kernel<<<dim3(4, 8, BB), 256, 0, stream>>>(Kb, Vb, S0, Z0, prefS, prefz);
  attn_kernel<<<dim3(8, NCH, BB), 256, 0, stream>>>(Kb, Qb, Vb, prefS, prefz, Zout, attn_o);
  ffn_kernel<<<NROW / 16, 256, 0, stream>>>(attn_o, Rb, W1, b1, W2, b2, out_main);
  s_write_kernel<<<dim3(8, NCH, BB), 512, 0, stream>>>(Kb, Vb, prefS, Sout);
}

// Round 3
// 381.905 us; speedup vs baseline: 1.0999x; 1.0531x over previous
//
#include <hip/hip_runtime.h>

// LinearAttentionBlock: B=8 T=512 FIN=256 D=128
// out   [B,T,D]    @ d_out + 0
// S_out [B,T,D*D]  @ d_out + 524288      (256 MiB -> HBM-write bound floor ~46us)
// Z     [B,T,D]    @ d_out + 524288 + 67108864

constexpr int BB = 8, TT = 512, FIN_ = 256, DD = 128;
constexpr int NROW = BB * TT;       // 4096
constexpr int CLEN = 64, NCH = 8;   // chunk length, chunks per batch (T = CLEN*NCH)
constexpr float CLAMPV = 1e20f;

typedef float f4v __attribute__((ext_vector_type(4)));

// ---------------- 1. LN fused into xn @ {Wk,Wq,Wv,Ws} GEMM, 64x64 tiles, 4x4 micro ----------------
__global__ __launch_bounds__(256) void gemm_qkvs(
    const float* __restrict__ x,
    const float* __restrict__ gamma, const float* __restrict__ beta,
    const float* __restrict__ Wk, const float* __restrict__ Wq,
    const float* __restrict__ Wv, const float* __restrict__ Ws,
    const float* __restrict__ bs,
    float* __restrict__ Kb, float* __restrict__ Qb,
    float* __restrict__ Vb, float* __restrict__ Rb)
{
  int ct = blockIdx.x, rt = blockIdx.y;
  int mat = ct >> 1, cb = (ct & 1) * 64;
  const float* W = (mat == 0) ? Wk : (mat == 1) ? Wq : (mat == 2) ? Wv : Ws;
  float* Ob      = (mat == 0) ? Kb : (mat == 1) ? Qb : (mat == 2) ? Vb : Rb;
  __shared__ float As[16][64];   // [k][m]
  __shared__ float Bs[16][64];   // [k][n]
  __shared__ float mu_s[64], rs_s[64];
  int tid = threadIdx.x;
  // ---- LN stats: 4 lanes per row ----
  {
    int row = tid >> 2, q = tid & 3;
    const float* xr = &x[(rt * 64 + row) * FIN_ + q * 64];
    float sum = 0.f, sq = 0.f;
#pragma unroll
    for (int u = 0; u < 16; u++) {
      float4 v = *(const float4*)&xr[u * 4];
      sum += v.x + v.y + v.z + v.w;
      sq  += v.x * v.x + v.y * v.y + v.z * v.z + v.w * v.w;
    }
    sum += __shfl_xor(sum, 1); sq += __shfl_xor(sq, 1);
    sum += __shfl_xor(sum, 2); sq += __shfl_xor(sq, 2);
    if (q == 0) {
      float mu = sum * (1.0f / FIN_);
      float var = sq * (1.0f / FIN_) - mu * mu;
      mu_s[row] = mu;
      rs_s[row] = rsqrtf(var + 1e-5f);
    }
  }
  __syncthreads();
  int tn = tid & 15, tm = tid >> 4;
  int lm = tid >> 2, lq = tid & 3;
  int lk = tid >> 4, ln4 = (tid & 15) * 4;
  float acc[4][4] = {};
  float mu = mu_s[lm], rs = rs_s[lm];
  for (int k0 = 0; k0 < FIN_; k0 += 16) {
    float4 av = *(const float4*)&x[(rt * 64 + lm) * FIN_ + k0 + lq * 4];
    float4 g  = *(const float4*)&gamma[k0 + lq * 4];
    float4 be = *(const float4*)&beta[k0 + lq * 4];
    As[lq * 4 + 0][lm] = (av.x - mu) * rs * g.x + be.x;
    As[lq * 4 + 1][lm] = (av.y - mu) * rs * g.y + be.y;
    As[lq * 4 + 2][lm] = (av.z - mu) * rs * g.z + be.z;
    As[lq * 4 + 3][lm] = (av.w - mu) * rs * g.w + be.w;
    *(float4*)&Bs[lk][ln4] = *(const float4*)&W[(k0 + lk) * DD + cb + ln4];
    __syncthreads();
#pragma unroll
    for (int k = 0; k < 16; k++) {
      float4 a = *(const float4*)&As[k][tm * 4];
      float4 b = *(const float4*)&Bs[k][tn * 4];
      float ar[4] = {a.x, a.y, a.z, a.w};
      float br[4] = {b.x, b.y, b.z, b.w};
#pragma unroll
      for (int i = 0; i < 4; i++)
#pragma unroll
        for (int j = 0; j < 4; j++) acc[i][j] += ar[i] * br[j];
    }
    __syncthreads();
  }
#pragma unroll
  for (int i = 0; i < 4; i++) {
    int row = rt * 64 + tm * 4 + i;
    int col = cb + tn * 4;
    float vals[4];
#pragma unroll
    for (int j = 0; j < 4; j++) {
      float v = acc[i][j];
      if (mat <= 1) v = (v > 0.f) ? v + 1.f : expf(v);   // phi = elu + 1
      else if (mat == 3) v += bs[col + j];
      vals[j] = v;
    }
    float4 o = make_float4(vals[0], vals[1], vals[2], vals[3]);
    *(float4*)&Ob[row * DD + col] = o;
  }
}

// ---------------- 2. chunk sums + exclusive scan fused: grid (4 jt, 8 it, BB) = 256 blocks ----------
__global__ __launch_bounds__(256) void prefix_kernel(
    const float* __restrict__ Kb, const float* __restrict__ Vb,
    const float* __restrict__ S0, const float* __restrict__ Z0,
    float* __restrict__ prefS, float* __restrict__ prefz)
{
  int jt = blockIdx.x, it = blockIdx.y, b = blockIdx.z;
  int i0 = it * 16, j0 = jt * 32;
  __shared__ float Ks[CLEN][16];   // 4 KB
  __shared__ float Vs[CLEN][32];   // 8 KB
  int tid = threadIdx.x;
  int il = tid >> 4, jl = tid & 15;
  float2 s0v = *(const float2*)&S0[b * DD * DD + (i0 + il) * DD + j0 + jl * 2];
  float acc0 = 0.f, acc1 = 0.f;
  float zacc = 0.f;
  float z0v = (jt == 0 && tid < 16) ? Z0[b * DD + i0 + tid] : 0.f;
  for (int c = 0; c < NCH; c++) {
    const float* Kc = Kb + (b * TT + c * CLEN) * DD;
    const float* Vc = Vb + (b * TT + c * CLEN) * DD;
    {
      int t = tid >> 2, i4 = (tid & 3) * 4;
      *(float4*)&Ks[t][i4] = *(const float4*)&Kc[t * DD + i0 + i4];
    }
#pragma unroll
    for (int u = 0; u < 2; u++) {
      int idx = u * 256 + tid;
      int t = idx >> 3, j4 = (idx & 7) * 4;
      *(float4*)&Vs[t][j4] = *(const float4*)&Vc[t * DD + j0 + j4];
    }
    __syncthreads();
    float2 op = make_float2(acc0 + s0v.x, acc1 + s0v.y);
    *(float2*)&prefS[(size_t)(b * NCH + c) * DD * DD + (i0 + il) * DD + j0 + jl * 2] = op;
    if (jt == 0 && tid < 16)
      prefz[(b * NCH + c) * DD + i0 + tid] = zacc + z0v;
#pragma unroll 8
    for (int t = 0; t < CLEN; t++) {
      float k = Ks[t][il];
      float2 v2 = *(const float2*)&Vs[t][jl * 2];
      acc0 += k * v2.x;
      acc1 += k * v2.y;
    }
    if (jt == 0 && tid < 16) {
      float z = 0.f;
#pragma unroll 8
      for (int t = 0; t < CLEN; t++) z += Ks[t][tid];
      zacc += z;
    }
    __syncthreads();
  }
}

// ---------------- 3. MEGA: attn(+FFN) and s_write roles in ONE launch ----------------
// grid (24, NCH, BB): x<8 -> attn role (sub=x, 8 t-rows, ends with FFN+residual -> out);
// x>=8 -> s_write role (it=x-8, 8 state rows, NT-stream 268 MB).
// Rationale: attn+ffn are compute/latency-bound, s_write is HBM-write-bound; co-residency
// on the CUs overlaps the two regimes instead of serializing them as separate launches.
union MegaSmem {
  struct {
    float KsT[DD][CLEN + 2];   // 33792 B
    float Qs[8][132];          //  4224 B
    float sc[8][CLEN + 2];     //  2112 B
    float zeff[DD];            //   512 B
    float den[8];              //    32 B
    float As[8][132];          //  4224 B
    float H1[8][132];          //  4224 B
  } a;                         // 49120 B
  struct {
    float Vs[CLEN][DD];        // 32768 B
    float Ksm[CLEN][8];        //  2048 B
  } s;
};

__global__ __launch_bounds__(256) void mega_kernel(
    const float* __restrict__ Kb, const float* __restrict__ Qb,
    const float* __restrict__ Vb, const float* __restrict__ prefS,
    const float* __restrict__ prefz, const float* __restrict__ Rb,
    const float* __restrict__ W1, const float* __restrict__ b1,
    const float* __restrict__ W2, const float* __restrict__ b2,
    float* __restrict__ Zout, float* __restrict__ out_main,
    float* __restrict__ Sout)
{
  __shared__ MegaSmem sm;
  int c = blockIdx.y, b = blockIdx.z, tid = threadIdx.x;
  const float* Kc = Kb + (b * TT + c * CLEN) * DD;
  const float* Vc = Vb + (b * TT + c * CLEN) * DD;

  if (blockIdx.x >= 8) {
    // ---------------- s_write role ----------------
    int it = blockIdx.x - 8;
    int i0 = it * 8;
#pragma unroll
    for (int u = 0; u < 8; u++) {
      int idx = u * 256 + tid;
      int t = idx >> 5, c4 = (idx & 31) * 4;
      *(float4*)&sm.s.Vs[t][c4] = *(const float4*)&Vc[t * DD + c4];
    }
#pragma unroll
    for (int u = 0; u < 2; u++) {
      int idx = u * 256 + tid;
      int t = idx >> 3, r = idx & 7;
      sm.s.Ksm[t][r] = Kc[t * DD + i0 + r];
    }
    __syncthreads();
    int irow = tid >> 5, jq = tid & 31;
    int j = jq * 4;
    float4 pref = *(const float4*)&prefS[(size_t)(b * NCH + c) * DD * DD + (i0 + irow) * DD + j];
    float4 acc = make_float4(0.f, 0.f, 0.f, 0.f);
    float* So = Sout + (size_t)(b * TT + c * CLEN) * (DD * DD) + (i0 + irow) * DD + j;
#pragma unroll 4
    for (int t = 0; t < CLEN; t++) {
      float4 v4 = *(const float4*)&sm.s.Vs[t][j];
      float kk = sm.s.Ksm[t][irow];
      acc.x += kk * v4.x; acc.y += kk * v4.y;
      acc.z += kk * v4.z; acc.w += kk * v4.w;
      f4v o4;
      o4.x = fminf(fmaxf(pref.x + acc.x, -CLAMPV), CLAMPV);
      o4.y = fminf(fmaxf(pref.y + acc.y, -CLAMPV), CLAMPV);
      o4.z = fminf(fmaxf(pref.z + acc.z, -CLAMPV), CLAMPV);
      o4.w = fminf(fmaxf(pref.w + acc.w, -CLAMPV), CLAMPV);
      __builtin_nontemporal_store(o4, (f4v*)&So[(size_t)t * (DD * DD)]);
    }
    return;
  }

  // ---------------- attn + FFN role ----------------
  int sub = blockIdx.x;
  int t0 = sub * 8;
  int tlim = t0 + 8;
  const float* Qc = Qb + (b * TT + c * CLEN) * DD;
  for (int idx = tid; idx < tlim * 32; idx += 256) {
    int t = idx >> 5, c4 = (idx & 31) * 4;
    float4 v = *(const float4*)&Kc[t * DD + c4];
    sm.a.KsT[c4 + 0][t] = v.x; sm.a.KsT[c4 + 1][t] = v.y;
    sm.a.KsT[c4 + 2][t] = v.z; sm.a.KsT[c4 + 3][t] = v.w;
  }
  {
    int r = tid >> 5, c4 = (tid & 31) * 4;
    float4 q = *(const float4*)&Qc[(t0 + r) * DD + c4];
    *(float4*)&sm.a.Qs[r][c4] = q;
  }
  if (tid < DD) sm.a.zeff[tid] = prefz[(b * NCH + c) * DD + tid];
  __syncthreads();
  // scores
  {
    int tm = tid >> 5, tn = tid & 31;
    int tau0 = tn * 2;
    if (tau0 < tlim) {
      float s0 = 0.f, s1 = 0.f;
#pragma unroll 8
      for (int k = 0; k < DD; k++) {
        float q = sm.a.Qs[tm][k];
        float2 kk = *(const float2*)&sm.a.KsT[k][tau0];
        s0 += q * kk.x;
        s1 += q * kk.y;
      }
      int t = t0 + tm;
      sm.a.sc[tm][tau0]     = (tau0     <= t) ? s0 : 0.f;
      sm.a.sc[tm][tau0 + 1] = (tau0 + 1 <= t) ? s1 : 0.f;
    }
  }
  __syncthreads();
  if (tid < 8) {
    int t = t0 + tid;
    float d = 0.f;
    for (int tau = 0; tau <= t; tau++) d += sm.a.sc[tid][tau];
    float dz = 0.f;
#pragma unroll 8
    for (int k = 0; k < DD; k++) dz += sm.a.Qs[tid][k] * sm.a.zeff[k];
    sm.a.den[tid] = d + dz + 1e-5f;
  }
  __syncthreads();
  // numerator -> As (LDS)
  int tl = tid & 31, r = tid >> 5;
  int l0 = tl * 4;
  {
    float n0[4] = {};
#pragma unroll 4
    for (int tau = 0; tau < tlim; tau++) {
      float4 v4 = *(const float4*)&Vc[tau * DD + l0];
      float s = sm.a.sc[r][tau];
      n0[0] += s * v4.x; n0[1] += s * v4.y; n0[2] += s * v4.z; n0[3] += s * v4.w;
    }
    const float* P = prefS + (size_t)(b * NCH + c) * DD * DD;
#pragma unroll 4
    for (int i = 0; i < DD; i++) {
      float4 p4 = *(const float4*)&P[i * DD + l0];
      float q = sm.a.Qs[r][i];
      n0[0] += q * p4.x; n0[1] += q * p4.y; n0[2] += q * p4.z; n0[3] += q * p4.w;
    }
    float dd = sm.a.den[r];
    float4 o = make_float4(n0[0] / dd, n0[1] / dd, n0[2] / dd, n0[3] / dd);
    *(float4*)&sm.a.As[r][l0] = o;
  }
  // Z output (sub==7 staged full K); overlaps with others' FFN
  if (sub == 7 && tid < DD) {
    int i = tid;
    float a = sm.a.zeff[i];
    for (int t = 0; t < CLEN; t++) {
      a += sm.a.KsT[i][t];
      a = fminf(fmaxf(a, -CLAMPV), CLAMPV);
      __builtin_nontemporal_store(a, &Zout[(size_t)(b * TT + c * CLEN + t) * DD + i]);
    }
  }
  __syncthreads();
  // FFN layer 1: H1 = relu(As @ W1 + b1)
  {
    float a1[4] = {};
#pragma unroll 8
    for (int k = 0; k < DD; k++) {
      float4 w = *(const float4*)&W1[k * DD + l0];
      float a = sm.a.As[r][k];
      a1[0] += a * w.x; a1[1] += a * w.y; a1[2] += a * w.z; a1[3] += a * w.w;
    }
    float4 bv = *(const float4*)&b1[l0];
    float4 h;
    h.x = fmaxf(a1[0] + bv.x, 0.f);
    h.y = fmaxf(a1[1] + bv.y, 0.f);
    h.z = fmaxf(a1[2] + bv.z, 0.f);
    h.w = fmaxf(a1[3] + bv.w, 0.f);
    *(float4*)&sm.a.H1[r][l0] = h;
  }
  __syncthreads();
  // FFN layer 2 + residual
  {
    float a2[4] = {};
#pragma unroll 8
    for (int k = 0; k < DD; k++) {
      float4 w = *(const float4*)&W2[k * DD + l0];
      float a = sm.a.H1[r][k];
      a2[0] += a * w.x; a2[1] += a * w.y; a2[2] += a * w.z; a2[3] += a * w.w;
    }
    int grow = b * TT + c * CLEN + t0 + r;
    float4 b2v = *(const float4*)&b2[l0];
    float4 rv = *(const float4*)&Rb[grow * DD + l0];
    float4 o;
    o.x = fmaxf(a2[0] + b2v.x, 0.f) + rv.x;
    o.y = fmaxf(a2[1] + b2v.y, 0.f) + rv.y;
    o.z = fmaxf(a2[2] + b2v.z, 0.f) + rv.z;
    o.w = fmaxf(a2[3] + b2v.w, 0.f) + rv.w;
    *(float4*)&out_main[grow * DD + l0] = o;
  }
}

extern "C" void kernel_launch(void* const* d_in, const int* in_sizes, int n_in,
                              void* d_out, int out_size, void* d_ws, size_t ws_size,
                              hipStream_t stream)
{
  const float* x     = (const float*)d_in[0];
  const float* S0    = (const float*)d_in[1];
  const float* Z0    = (const float*)d_in[2];
  const float* gamma = (const float*)d_in[3];
  const float* beta  = (const float*)d_in[4];
  const float* Wk    = (const float*)d_in[5];
  const float* Wq    = (const float*)d_in[6];
  const float* Wv    = (const float*)d_in[7];
  const float* W1    = (const float*)d_in[8];
  const float* b1    = (const float*)d_in[9];
  const float* W2    = (const float*)d_in[10];
  const float* b2    = (const float*)d_in[11];
  const float* Ws    = (const float*)d_in[12];
  const float* bs    = (const float*)d_in[13];

  float* out_main = (float*)d_out;                       // [B,T,D]
  float* Sout = out_main + NROW * DD;                    // [B,T,D*D]
  float* Zout = Sout + (size_t)NROW * DD * DD;           // [B,T,D]

  float* ws_f   = (float*)d_ws;
  float* Kb     = ws_f;                  // 524288
  float* Qb     = Kb + 524288;           // 524288
  float* Vb     = Qb + 524288;           // 524288
  float* Rb     = Vb + 524288;           // 524288  (xn@Ws + bs)
  float* prefS  = Rb + 524288;           // 1048576 (exclusive prefix + S0)
  float* prefz  = prefS + 1048576;       // 8192    (exclusive prefix + Z0)

  gemm_qkvs<<<dim3(8, 64), 256, 0, stream>>>(x, gamma, beta, Wk, Wq, Wv, Ws, bs,
                                             Kb, Qb, Vb, Rb);
  prefix_kernel<<<dim3(4, 8, BB), 256, 0, stream>>>(Kb, Vb, S0, Z0, prefS, prefz);
  mega_kernel<<<dim3(24, NCH, BB), 256, 0, stream>>>(Kb, Qb, Vb, prefS, prefz, Rb,
                                                     W1, b1, W2, b2,
                                                     Zout, out_main, Sout);
}

// Round 5
// 373.879 us; speedup vs baseline: 1.1235x; 1.0215x over previous
//
#include <hip/hip_runtime.h>

// LinearAttentionBlock: B=8 T=512 FIN=256 D=128
// out   [B,T,D]    @ d_out + 0
// S_out [B,T,D*D]  @ d_out + 524288      (256 MiB -> HBM-write bound floor ~46us)
// Z     [B,T,D]    @ d_out + 524288 + 67108864
//
// NOTE (round-4 post-mortem): single cooperative grid.sync mega-kernel corrupted
// S_out (stale/raced data on a subset of tiles) while out passed -> grid-wide
// fusion is off the table. 3-launch structure below is the verified anchor.

constexpr int BB = 8, TT = 512, FIN_ = 256, DD = 128;
constexpr int NROW = BB * TT;       // 4096
constexpr int CLEN = 64, NCH = 8;   // chunk length, chunks per batch
constexpr float CLAMPV = 1e20f;

typedef float f4v __attribute__((ext_vector_type(4)));

// ---------------- 1. LN fused into xn @ {Wk,Wq,Wv,Ws} GEMM, 64x64 tiles ----------------
// Double-buffered LDS: one barrier per k-step, global prefetch overlaps compute.
__global__ __launch_bounds__(256) void gemm_qkvs(
    const float* __restrict__ x,
    const float* __restrict__ gamma, const float* __restrict__ beta,
    const float* __restrict__ Wk, const float* __restrict__ Wq,
    const float* __restrict__ Wv, const float* __restrict__ Ws,
    const float* __restrict__ bs,
    float* __restrict__ Kb, float* __restrict__ Qb,
    float* __restrict__ Vb, float* __restrict__ Rb)
{
  int ct = blockIdx.x, rt = blockIdx.y;
  int mat = ct >> 1, cb = (ct & 1) * 64;
  const float* W = (mat == 0) ? Wk : (mat == 1) ? Wq : (mat == 2) ? Wv : Ws;
  float* Ob      = (mat == 0) ? Kb : (mat == 1) ? Qb : (mat == 2) ? Vb : Rb;
  __shared__ float As[2][16][64];   // [buf][k][m]
  __shared__ float Bs[2][16][64];   // [buf][k][n]
  __shared__ float mu_s[64], rs_s[64];
  int tid = threadIdx.x;
  // ---- LN stats: 4 lanes per row ----
  {
    int row = tid >> 2, q = tid & 3;
    const float* xr = &x[(rt * 64 + row) * FIN_ + q * 64];
    float sum = 0.f, sq = 0.f;
#pragma unroll
    for (int u = 0; u < 16; u++) {
      float4 v = *(const float4*)&xr[u * 4];
      sum += v.x + v.y + v.z + v.w;
      sq  += v.x * v.x + v.y * v.y + v.z * v.z + v.w * v.w;
    }
    sum += __shfl_xor(sum, 1); sq += __shfl_xor(sq, 1);
    sum += __shfl_xor(sum, 2); sq += __shfl_xor(sq, 2);
    if (q == 0) {
      float mu = sum * (1.0f / FIN_);
      float var = sq * (1.0f / FIN_) - mu * mu;
      mu_s[row] = mu;
      rs_s[row] = rsqrtf(var + 1e-5f);
    }
  }
  __syncthreads();
  int tn = tid & 15, tm = tid >> 4;
  int lm = tid >> 2, lq = tid & 3;
  int lk = tid >> 4, ln4 = (tid & 15) * 4;
  float acc[4][4] = {};
  float mu = mu_s[lm], rs = rs_s[lm];
  // prologue: prefetch k0 = 0
  float4 xa = *(const float4*)&x[(rt * 64 + lm) * FIN_ + lq * 4];
  float4 ga = *(const float4*)&gamma[lq * 4];
  float4 be = *(const float4*)&beta[lq * 4];
  float4 wb = *(const float4*)&W[lk * DD + cb + ln4];
  int cur = 0;
  for (int k0 = 0; k0 < FIN_; k0 += 16) {
    As[cur][lq * 4 + 0][lm] = (xa.x - mu) * rs * ga.x + be.x;
    As[cur][lq * 4 + 1][lm] = (xa.y - mu) * rs * ga.y + be.y;
    As[cur][lq * 4 + 2][lm] = (xa.z - mu) * rs * ga.z + be.z;
    As[cur][lq * 4 + 3][lm] = (xa.w - mu) * rs * ga.w + be.w;
    *(float4*)&Bs[cur][lk][ln4] = wb;
    if (k0 + 16 < FIN_) {           // prefetch next slice; latency hides under barrier+compute
      xa = *(const float4*)&x[(rt * 64 + lm) * FIN_ + k0 + 16 + lq * 4];
      ga = *(const float4*)&gamma[k0 + 16 + lq * 4];
      be = *(const float4*)&beta[k0 + 16 + lq * 4];
      wb = *(const float4*)&W[(k0 + 16 + lk) * DD + cb + ln4];
    }
    __syncthreads();
#pragma unroll
    for (int k = 0; k < 16; k++) {
      float4 a = *(const float4*)&As[cur][k][tm * 4];
      float4 b = *(const float4*)&Bs[cur][k][tn * 4];
      float ar[4] = {a.x, a.y, a.z, a.w};
      float br[4] = {b.x, b.y, b.z, b.w};
#pragma unroll
      for (int i = 0; i < 4; i++)
#pragma unroll
        for (int j = 0; j < 4; j++) acc[i][j] += ar[i] * br[j];
    }
    cur ^= 1;
  }
#pragma unroll
  for (int i = 0; i < 4; i++) {
    int row = rt * 64 + tm * 4 + i;
    int col = cb + tn * 4;
    float vals[4];
#pragma unroll
    for (int j = 0; j < 4; j++) {
      float v = acc[i][j];
      if (mat <= 1) v = (v > 0.f) ? v + 1.f : expf(v);   // phi = elu + 1
      else if (mat == 3) v += bs[col + j];
      vals[j] = v;
    }
    *(float4*)&Ob[row * DD + col] = make_float4(vals[0], vals[1], vals[2], vals[3]);
  }
}

// ---------------- 2. chunk sums + exclusive scan, dbuf: grid (4 jt, 8 it, BB) ----------------
__global__ __launch_bounds__(256) void prefix_kernel(
    const float* __restrict__ Kb, const float* __restrict__ Vb,
    const float* __restrict__ S0, const float* __restrict__ Z0,
    float* __restrict__ prefS, float* __restrict__ prefz)
{
  int jt = blockIdx.x, it = blockIdx.y, b = blockIdx.z;
  int i0 = it * 16, j0 = jt * 32;
  __shared__ float Ks[2][CLEN][16];   // 8 KB
  __shared__ float Vs[2][CLEN][32];   // 16 KB
  int tid = threadIdx.x;
  int il = tid >> 4, jl = tid & 15;
  float2 s0v = *(const float2*)&S0[b * DD * DD + (i0 + il) * DD + j0 + jl * 2];
  float acc0 = 0.f, acc1 = 0.f;
  float zacc = 0.f;
  float z0v = (jt == 0 && tid < 16) ? Z0[b * DD + i0 + tid] : 0.f;
  // stage chunk 0 into buf 0
  {
    const float* Kc = Kb + (b * TT) * DD;
    const float* Vc = Vb + (b * TT) * DD;
    int t = tid >> 2, i4 = (tid & 3) * 4;
    *(float4*)&Ks[0][t][i4] = *(const float4*)&Kc[t * DD + i0 + i4];
#pragma unroll
    for (int u = 0; u < 2; u++) {
      int idx = u * 256 + tid;
      int tv = idx >> 3, j4 = (idx & 7) * 4;
      *(float4*)&Vs[0][tv][j4] = *(const float4*)&Vc[tv * DD + j0 + j4];
    }
  }
  int cur = 0;
  for (int c = 0; c < NCH; c++) {
    __syncthreads();                 // buf[cur] staged
    float4 kq, vq0, vq1;
    if (c + 1 < NCH) {               // prefetch next chunk to regs (overlaps compute)
      const float* Kc = Kb + (b * TT + (c + 1) * CLEN) * DD;
      const float* Vc = Vb + (b * TT + (c + 1) * CLEN) * DD;
      kq  = *(const float4*)&Kc[(tid >> 2) * DD + i0 + (tid & 3) * 4];
      vq0 = *(const float4*)&Vc[(tid >> 3) * DD + j0 + (tid & 7) * 4];
      int idx = 256 + tid;
      vq1 = *(const float4*)&Vc[(idx >> 3) * DD + j0 + (idx & 7) * 4];
    }
    // exclusive prefix out
    float2 op = make_float2(acc0 + s0v.x, acc1 + s0v.y);
    *(float2*)&prefS[(size_t)(b * NCH + c) * DD * DD + (i0 + il) * DD + j0 + jl * 2] = op;
    if (jt == 0 && tid < 16)
      prefz[(b * NCH + c) * DD + i0 + tid] = zacc + z0v;
    // accumulate this chunk (order identical to verified kernel)
#pragma unroll 8
    for (int t = 0; t < CLEN; t++) {
      float k = Ks[cur][t][il];
      float2 v2 = *(const float2*)&Vs[cur][t][jl * 2];
      acc0 += k * v2.x;
      acc1 += k * v2.y;
    }
    if (jt == 0 && tid < 16) {
      float z = 0.f;
#pragma unroll 8
      for (int t = 0; t < CLEN; t++) z += Ks[cur][t][tid];
      zacc += z;
    }
    if (c + 1 < NCH) {               // write prefetched regs into the other buffer
      *(float4*)&Ks[cur ^ 1][tid >> 2][(tid & 3) * 4] = kq;
      *(float4*)&Vs[cur ^ 1][tid >> 3][(tid & 7) * 4] = vq0;
      int idx = 256 + tid;
      *(float4*)&Vs[cur ^ 1][idx >> 3][(idx & 7) * 4] = vq1;
    }
    cur ^= 1;
  }
}

// ---------------- 3. MEGA: attn(+FFN) and s_write roles in ONE launch ----------------
// grid (16, NCH, BB): x<8 -> attn role (8 t-rows, FFN+residual -> out);
// x>=8 -> s_write role (16 state rows -> halves the redundant V staging vs 8-row roles).
union MegaSmem {
  struct {
    float KsT[DD][CLEN + 2];   // 33792 B
    float Qs[8][132];          //  4224 B
    float sc[8][CLEN + 2];     //  2112 B
    float zeff[DD];            //   512 B
    float den[8];              //    32 B
    float As[8][132];          //  4224 B
    float H1[8][132];          //  4224 B
  } a;                         // 49120 B
  struct {
    float Vs[CLEN][DD];        // 32768 B
    float Ksm[CLEN][16];       //  4096 B
  } s;
};

__global__ __launch_bounds__(256) void mega_kernel(
    const float* __restrict__ Kb, const float* __restrict__ Qb,
    const float* __restrict__ Vb, const float* __restrict__ prefS,
    const float* __restrict__ prefz, const float* __restrict__ Rb,
    const float* __restrict__ W1, const float* __restrict__ b1,
    const float* __restrict__ W2, const float* __restrict__ b2,
    float* __restrict__ Zout, float* __restrict__ out_main,
    float* __restrict__ Sout)
{
  __shared__ MegaSmem sm;
  int c = blockIdx.y, b = blockIdx.z, tid = threadIdx.x;
  const float* Kc = Kb + (b * TT + c * CLEN) * DD;
  const float* Vc = Vb + (b * TT + c * CLEN) * DD;

  if (blockIdx.x >= 8) {
    // ---------------- s_write role: 16 state rows, NT-stream ----------------
    int i0 = (blockIdx.x - 8) * 16;
#pragma unroll
    for (int u = 0; u < 8; u++) {
      int idx = u * 256 + tid;
      int t = idx >> 5, c4 = (idx & 31) * 4;
      *(float4*)&sm.s.Vs[t][c4] = *(const float4*)&Vc[t * DD + c4];
    }
#pragma unroll
    for (int u = 0; u < 4; u++) {
      int idx = u * 256 + tid;
      int t = idx >> 4, r = idx & 15;
      sm.s.Ksm[t][r] = Kc[t * DD + i0 + r];
    }
    __syncthreads();
    int irow = tid >> 5, jq = tid & 31;
    int j = jq * 4;
    size_t pbase = (size_t)(b * NCH + c) * DD * DD;
    float4 prefA = *(const float4*)&prefS[pbase + (i0 + irow) * DD + j];
    float4 prefB = *(const float4*)&prefS[pbase + (i0 + 8 + irow) * DD + j];
    float4 accA = make_float4(0.f, 0.f, 0.f, 0.f);
    float4 accB = make_float4(0.f, 0.f, 0.f, 0.f);
    float* SoA = Sout + (size_t)(b * TT + c * CLEN) * (DD * DD) + (i0 + irow) * DD + j;
    float* SoB = SoA + 8 * DD;
#pragma unroll 2
    for (int t = 0; t < CLEN; t++) {
      float4 v4 = *(const float4*)&sm.s.Vs[t][j];
      float kA = sm.s.Ksm[t][irow];
      float kB = sm.s.Ksm[t][irow + 8];
      accA.x += kA * v4.x; accA.y += kA * v4.y;
      accA.z += kA * v4.z; accA.w += kA * v4.w;
      f4v oA;
      oA.x = fminf(fmaxf(prefA.x + accA.x, -CLAMPV), CLAMPV);
      oA.y = fminf(fmaxf(prefA.y + accA.y, -CLAMPV), CLAMPV);
      oA.z = fminf(fmaxf(prefA.z + accA.z, -CLAMPV), CLAMPV);
      oA.w = fminf(fmaxf(prefA.w + accA.w, -CLAMPV), CLAMPV);
      __builtin_nontemporal_store(oA, (f4v*)&SoA[(size_t)t * (DD * DD)]);
      accB.x += kB * v4.x; accB.y += kB * v4.y;
      accB.z += kB * v4.z; accB.w += kB * v4.w;
      f4v oB;
      oB.x = fminf(fmaxf(prefB.x + accB.x, -CLAMPV), CLAMPV);
      oB.y = fminf(fmaxf(prefB.y + accB.y, -CLAMPV), CLAMPV);
      oB.z = fminf(fmaxf(prefB.z + accB.z, -CLAMPV), CLAMPV);
      oB.w = fminf(fmaxf(prefB.w + accB.w, -CLAMPV), CLAMPV);
      __builtin_nontemporal_store(oB, (f4v*)&SoB[(size_t)t * (DD * DD)]);
    }
    return;
  }

  // ---------------- attn + FFN role: 8 t-rows ----------------
  int sub = blockIdx.x;
  int t0 = sub * 8;
  int tlim = t0 + 8;
  const float* Qc = Qb + (b * TT + c * CLEN) * DD;
  for (int idx = tid; idx < tlim * 32; idx += 256) {
    int t = idx >> 5, c4 = (idx & 31) * 4;
    float4 vv = *(const float4*)&Kc[t * DD + c4];
    sm.a.KsT[c4 + 0][t] = vv.x; sm.a.KsT[c4 + 1][t] = vv.y;
    sm.a.KsT[c4 + 2][t] = vv.z; sm.a.KsT[c4 + 3][t] = vv.w;
  }
  {
    int r = tid >> 5, c4 = (tid & 31) * 4;
    *(float4*)&sm.a.Qs[r][c4] = *(const float4*)&Qc[(t0 + r) * DD + c4];
  }
  if (tid < DD) sm.a.zeff[tid] = prefz[(b * NCH + c) * DD + tid];
  __syncthreads();
  // scores
  {
    int tm = tid >> 5, tn = tid & 31;
    int tau0 = tn * 2;
    if (tau0 < tlim) {
      float s0 = 0.f, s1 = 0.f;
#pragma unroll 8
      for (int k = 0; k < DD; k++) {
        float q = sm.a.Qs[tm][k];
        float2 kk = *(const float2*)&sm.a.KsT[k][tau0];
        s0 += q * kk.x;
        s1 += q * kk.y;
      }
      int t = t0 + tm;
      sm.a.sc[tm][tau0]     = (tau0     <= t) ? s0 : 0.f;
      sm.a.sc[tm][tau0 + 1] = (tau0 + 1 <= t) ? s1 : 0.f;
    }
  }
  __syncthreads();
  // den: all 256 threads (32 lanes per row), shuffle-reduce (was 8 serial threads)
  {
    int r = tid >> 5, g = tid & 31;
    int t = t0 + r;
    float p = 0.f;
    for (int tau = g; tau <= t; tau += 32) p += sm.a.sc[r][tau];
#pragma unroll 4
    for (int k = g; k < DD; k += 32) p += sm.a.Qs[r][k] * sm.a.zeff[k];
#pragma unroll
    for (int off = 1; off < 32; off <<= 1) p += __shfl_xor(p, off);
    if (g == 0) sm.a.den[r] = p + 1e-5f;
  }
  __syncthreads();
  // numerator -> As (LDS)
  int tl = tid & 31, r = tid >> 5;
  int l0 = tl * 4;
  {
    float n0[4] = {};
#pragma unroll 4
    for (int tau = 0; tau < tlim; tau++) {
      float4 v4 = *(const float4*)&Vc[tau * DD + l0];
      float s = sm.a.sc[r][tau];
      n0[0] += s * v4.x; n0[1] += s * v4.y; n0[2] += s * v4.z; n0[3] += s * v4.w;
    }
    const float* P = prefS + (size_t)(b * NCH + c) * DD * DD;
#pragma unroll 4
    for (int i = 0; i < DD; i++) {
      float4 p4 = *(const float4*)&P[i * DD + l0];
      float q = sm.a.Qs[r][i];
      n0[0] += q * p4.x; n0[1] += q * p4.y; n0[2] += q * p4.z; n0[3] += q * p4.w;
    }
    float dd = sm.a.den[r];
    *(float4*)&sm.a.As[r][l0] =
        make_float4(n0[0] / dd, n0[1] / dd, n0[2] / dd, n0[3] / dd);
  }
  // Z output: sub==7 has full K staged
  if (sub == 7 && tid < DD) {
    int i = tid;
    float a = sm.a.zeff[i];
    for (int t = 0; t < CLEN; t++) {
      a += sm.a.KsT[i][t];
      a = fminf(fmaxf(a, -CLAMPV), CLAMPV);
      __builtin_nontemporal_store(a, &Zout[(size_t)(b * TT + c * CLEN + t) * DD + i]);
    }
  }
  __syncthreads();
  // FFN layer 1
  {
    float a1[4] = {};
#pragma unroll 8
    for (int k = 0; k < DD; k++) {
      float4 w = *(const float4*)&W1[k * DD + l0];
      float a = sm.a.As[r][k];
      a1[0] += a * w.x; a1[1] += a * w.y; a1[2] += a * w.z; a1[3] += a * w.w;
    }
    float4 bv = *(const float4*)&b1[l0];
    float4 h;
    h.x = fmaxf(a1[0] + bv.x, 0.f);
    h.y = fmaxf(a1[1] + bv.y, 0.f);
    h.z = fmaxf(a1[2] + bv.z, 0.f);
    h.w = fmaxf(a1[3] + bv.w, 0.f);
    *(float4*)&sm.a.H1[r][l0] = h;
  }
  __syncthreads();
  // FFN layer 2 + residual
  {
    float a2[4] = {};
#pragma unroll 8
    for (int k = 0; k < DD; k++) {
      float4 w = *(const float4*)&W2[k * DD + l0];
      float a = sm.a.H1[r][k];
      a2[0] += a * w.x; a2[1] += a * w.y; a2[2] += a * w.z; a2[3] += a * w.w;
    }
    int grow = b * TT + c * CLEN + t0 + r;
    float4 b2v = *(const float4*)&b2[l0];
    float4 rv = *(const float4*)&Rb[grow * DD + l0];
    float4 o;
    o.x = fmaxf(a2[0] + b2v.x, 0.f) + rv.x;
    o.y = fmaxf(a2[1] + b2v.y, 0.f) + rv.y;
    o.z = fmaxf(a2[2] + b2v.z, 0.f) + rv.z;
    o.w = fmaxf(a2[3] + b2v.w, 0.f) + rv.w;
    *(float4*)&out_main[grow * DD + l0] = o;
  }
}

extern "C" void kernel_launch(void* const* d_in, const int* in_sizes, int n_in,
                              void* d_out, int out_size, void* d_ws, size_t ws_size,
                              hipStream_t stream)
{
  const float* x     = (const float*)d_in[0];
  const float* S0    = (const float*)d_in[1];
  const float* Z0    = (const float*)d_in[2];
  const float* gamma = (const float*)d_in[3];
  const float* beta  = (const float*)d_in[4];
  const float* Wk    = (const float*)d_in[5];
  const float* Wq    = (const float*)d_in[6];
  const float* Wv    = (const float*)d_in[7];
  const float* W1    = (const float*)d_in[8];
  const float* b1    = (const float*)d_in[9];
  const float* W2    = (const float*)d_in[10];
  const float* b2    = (const float*)d_in[11];
  const float* Ws    = (const float*)d_in[12];
  const float* bs    = (const float*)d_in[13];

  float* out_main = (float*)d_out;                       // [B,T,D]
  float* Sout = out_main + NROW * DD;                    // [B,T,D*D]
  float* Zout = Sout + (size_t)NROW * DD * DD;           // [B,T,D]

  float* ws_f   = (float*)d_ws;
  float* Kb     = ws_f;                  // 524288
  float* Qb     = Kb + 524288;           // 524288
  float* Vb     = Qb + 524288;           // 524288
  float* Rb     = Vb + 524288;           // 524288  (xn@Ws + bs)
  float* prefS  = Rb + 524288;           // 1048576 (exclusive prefix + S0)
  float* prefz  = prefS + 1048576;       // 8192    (exclusive prefix + Z0)

  gemm_qkvs<<<dim3(8, 64), 256, 0, stream>>>(x, gamma, beta, Wk, Wq, Wv, Ws, bs,
                                             Kb, Qb, Vb, Rb);
  prefix_kernel<<<dim3(4, 8, BB), 256, 0, stream>>>(Kb, Vb, S0, Z0, prefS, prefz);
  mega_kernel<<<dim3(16, NCH, BB), 256, 0, stream>>>(Kb, Qb, Vb, prefS, prefz, Rb,
                                                     W1, b1, W2, b2,
                                                     Zout, out_main, Sout);
}

// Round 6
// 364.477 us; speedup vs baseline: 1.1524x; 1.0258x over previous
//
#include <hip/hip_runtime.h>

// LinearAttentionBlock: B=8 T=512 FIN=256 D=128
// out   [B,T,D]    @ d_out + 0
// S_out [B,T,D*D]  @ d_out + 524288      (256 MiB -> HBM-write bound floor ~43us)
// Z     [B,T,D]    @ d_out + 524288 + 67108864
//
// Round-6 structure: S_out emission FUSED into the prefix scan (the per-chunk
// t-loop already computes the within-chunk cumsum s_write used to redo).
// Pipeline: gemm_qkvs -> prefix(+S_out NT stream) -> attn(+FFN).
// (Round-4 note: cooperative grid.sync mega-fusion corrupted S_out -> off the table.)

constexpr int BB = 8, TT = 512, FIN_ = 256, DD = 128;
constexpr int NROW = BB * TT;       // 4096
constexpr int CLEN = 64, NCH = 8;   // chunk length, chunks per batch
constexpr float CLAMPV = 1e20f;

typedef float f4v __attribute__((ext_vector_type(4)));
typedef float f2v __attribute__((ext_vector_type(2)));

// ---------------- 1. LN fused into xn @ {Wk,Wq,Wv,Ws} GEMM, 64x64 tiles, dbuf ----------------
__global__ __launch_bounds__(256) void gemm_qkvs(
    const float* __restrict__ x,
    const float* __restrict__ gamma, const float* __restrict__ beta,
    const float* __restrict__ Wk, const float* __restrict__ Wq,
    const float* __restrict__ Wv, const float* __restrict__ Ws,
    const float* __restrict__ bs,
    float* __restrict__ Kb, float* __restrict__ Qb,
    float* __restrict__ Vb, float* __restrict__ Rb)
{
  int ct = blockIdx.x, rt = blockIdx.y;
  int mat = ct >> 1, cb = (ct & 1) * 64;
  const float* W = (mat == 0) ? Wk : (mat == 1) ? Wq : (mat == 2) ? Wv : Ws;
  float* Ob      = (mat == 0) ? Kb : (mat == 1) ? Qb : (mat == 2) ? Vb : Rb;
  __shared__ float As[2][16][64];   // [buf][k][m]
  __shared__ float Bs[2][16][64];   // [buf][k][n]
  __shared__ float mu_s[64], rs_s[64];
  int tid = threadIdx.x;
  // ---- LN stats: 4 lanes per row ----
  {
    int row = tid >> 2, q = tid & 3;
    const float* xr = &x[(rt * 64 + row) * FIN_ + q * 64];
    float sum = 0.f, sq = 0.f;
#pragma unroll
    for (int u = 0; u < 16; u++) {
      float4 v = *(const float4*)&xr[u * 4];
      sum += v.x + v.y + v.z + v.w;
      sq  += v.x * v.x + v.y * v.y + v.z * v.z + v.w * v.w;
    }
    sum += __shfl_xor(sum, 1); sq += __shfl_xor(sq, 1);
    sum += __shfl_xor(sum, 2); sq += __shfl_xor(sq, 2);
    if (q == 0) {
      float mu = sum * (1.0f / FIN_);
      float var = sq * (1.0f / FIN_) - mu * mu;
      mu_s[row] = mu;
      rs_s[row] = rsqrtf(var + 1e-5f);
    }
  }
  __syncthreads();
  int tn = tid & 15, tm = tid >> 4;
  int lm = tid >> 2, lq = tid & 3;
  int lk = tid >> 4, ln4 = (tid & 15) * 4;
  float acc[4][4] = {};
  float mu = mu_s[lm], rs = rs_s[lm];
  float4 xa = *(const float4*)&x[(rt * 64 + lm) * FIN_ + lq * 4];
  float4 ga = *(const float4*)&gamma[lq * 4];
  float4 be = *(const float4*)&beta[lq * 4];
  float4 wb = *(const float4*)&W[lk * DD + cb + ln4];
  int cur = 0;
  for (int k0 = 0; k0 < FIN_; k0 += 16) {
    As[cur][lq * 4 + 0][lm] = (xa.x - mu) * rs * ga.x + be.x;
    As[cur][lq * 4 + 1][lm] = (xa.y - mu) * rs * ga.y + be.y;
    As[cur][lq * 4 + 2][lm] = (xa.z - mu) * rs * ga.z + be.z;
    As[cur][lq * 4 + 3][lm] = (xa.w - mu) * rs * ga.w + be.w;
    *(float4*)&Bs[cur][lk][ln4] = wb;
    if (k0 + 16 < FIN_) {
      xa = *(const float4*)&x[(rt * 64 + lm) * FIN_ + k0 + 16 + lq * 4];
      ga = *(const float4*)&gamma[k0 + 16 + lq * 4];
      be = *(const float4*)&beta[k0 + 16 + lq * 4];
      wb = *(const float4*)&W[(k0 + 16 + lk) * DD + cb + ln4];
    }
    __syncthreads();
#pragma unroll
    for (int k = 0; k < 16; k++) {
      float4 a = *(const float4*)&As[cur][k][tm * 4];
      float4 b = *(const float4*)&Bs[cur][k][tn * 4];
      float ar[4] = {a.x, a.y, a.z, a.w};
      float br[4] = {b.x, b.y, b.z, b.w};
#pragma unroll
      for (int i = 0; i < 4; i++)
#pragma unroll
        for (int j = 0; j < 4; j++) acc[i][j] += ar[i] * br[j];
    }
    cur ^= 1;
  }
#pragma unroll
  for (int i = 0; i < 4; i++) {
    int row = rt * 64 + tm * 4 + i;
    int col = cb + tn * 4;
    float vals[4];
#pragma unroll
    for (int j = 0; j < 4; j++) {
      float v = acc[i][j];
      if (mat <= 1) v = (v > 0.f) ? v + 1.f : expf(v);   // phi = elu + 1
      else if (mat == 3) v += bs[col + j];
      vals[j] = v;
    }
    *(float4*)&Ob[row * DD + col] = make_float4(vals[0], vals[1], vals[2], vals[3]);
  }
}

// ---------------- 2. prefix scan + fused S_out stream: grid (2 jh, 16 it, BB) ----------------
// Block owns 8 i-rows x 64 j-cols. Per chunk: write exclusive prefix (prefS), then scan
// t=0..63 keeping TWO accumulators: acc (continuous chain -> prefS, order preserved) and
// accW (restarts per chunk -> S_out[t] = pref + accW, bit-identical to the old s_write).
// S_out is NT-streamed (write-once 268 MB); 256B contiguous segments per wave row.
__global__ __launch_bounds__(256) void prefix_kernel(
    const float* __restrict__ Kb, const float* __restrict__ Vb,
    const float* __restrict__ S0, const float* __restrict__ Z0,
    float* __restrict__ prefS, float* __restrict__ prefz,
    float* __restrict__ Sout)
{
  int jh = blockIdx.x, it = blockIdx.y, b = blockIdx.z;
  int i0 = it * 8, j0 = jh * 64;
  __shared__ float Ks[2][CLEN][8];    //  4 KB
  __shared__ float Vs[2][CLEN][64];   // 32 KB
  int tid = threadIdx.x;
  int il = tid >> 5, jl = tid & 31;   // row i0+il, cols j0+2jl, +1
  float2 s0v = *(const float2*)&S0[b * DD * DD + (i0 + il) * DD + j0 + jl * 2];
  float acc0 = 0.f, acc1 = 0.f, zacc = 0.f;
  float z0v = (jh == 0 && tid < 8) ? Z0[b * DD + i0 + tid] : 0.f;
  // stage chunk 0 into buf 0
  {
    const float* Kc = Kb + (b * TT) * DD;
    const float* Vc = Vb + (b * TT) * DD;
    int t = tid >> 2, i2 = (tid & 3) * 2;
    *(float2*)&Ks[0][t][i2] = *(const float2*)&Kc[t * DD + i0 + i2];
#pragma unroll
    for (int u = 0; u < 4; u++) {
      int idx = u * 256 + tid;
      int tv = idx >> 4, j4 = (idx & 15) * 4;
      *(float4*)&Vs[0][tv][j4] = *(const float4*)&Vc[tv * DD + j0 + j4];
    }
  }
  int cur = 0;
  for (int c = 0; c < NCH; c++) {
    __syncthreads();                  // buf[cur] staged
    float2 kq;
    float4 vq[4];
    if (c + 1 < NCH) {                // prefetch next chunk to regs
      const float* Kc = Kb + (b * TT + (c + 1) * CLEN) * DD;
      const float* Vc = Vb + (b * TT + (c + 1) * CLEN) * DD;
      kq = *(const float2*)&Kc[(tid >> 2) * DD + i0 + (tid & 3) * 2];
#pragma unroll
      for (int u = 0; u < 4; u++) {
        int idx = u * 256 + tid;
        vq[u] = *(const float4*)&Vc[(idx >> 4) * DD + j0 + (idx & 15) * 4];
      }
    }
    // exclusive prefix out (cached: consumed by attn next launch)
    float p0 = acc0 + s0v.x, p1 = acc1 + s0v.y;
    *(float2*)&prefS[(size_t)(b * NCH + c) * DD * DD + (i0 + il) * DD + j0 + jl * 2] =
        make_float2(p0, p1);
    if (jh == 0 && tid < 8)
      prefz[(b * NCH + c) * DD + i0 + tid] = zacc + z0v;
    // scan chunk: acc chain (prefS semantics) + accW (S_out within-chunk cumsum)
    float w0 = 0.f, w1 = 0.f;
    float* So = Sout + (size_t)(b * TT + c * CLEN) * (DD * DD) + (i0 + il) * DD + j0 + jl * 2;
#pragma unroll 4
    for (int t = 0; t < CLEN; t++) {
      float k = Ks[cur][t][il];
      float2 v2 = *(const float2*)&Vs[cur][t][jl * 2];
      acc0 += k * v2.x; acc1 += k * v2.y;
      w0 += k * v2.x;   w1 += k * v2.y;
      f2v o2;
      o2.x = fminf(fmaxf(p0 + w0, -CLAMPV), CLAMPV);
      o2.y = fminf(fmaxf(p1 + w1, -CLAMPV), CLAMPV);
      __builtin_nontemporal_store(o2, (f2v*)&So[(size_t)t * (DD * DD)]);
    }
    if (jh == 0 && tid < 8) {
      float z = 0.f;
#pragma unroll 8
      for (int t = 0; t < CLEN; t++) z += Ks[cur][t][tid];
      zacc += z;
    }
    if (c + 1 < NCH) {                // write prefetched regs into other buffer
      *(float2*)&Ks[cur ^ 1][tid >> 2][(tid & 3) * 2] = kq;
#pragma unroll
      for (int u = 0; u < 4; u++) {
        int idx = u * 256 + tid;
        *(float4*)&Vs[cur ^ 1][idx >> 4][(idx & 15) * 4] = vq[u];
      }
    }
    cur ^= 1;
  }
}

// ---------------- 3. attn + FFN: grid (8 sub, NCH, BB) = 512 blocks, 3/CU ----------------
__global__ __launch_bounds__(256) void attn_kernel(
    const float* __restrict__ Kb, const float* __restrict__ Qb,
    const float* __restrict__ Vb, const float* __restrict__ prefS,
    const float* __restrict__ prefz, const float* __restrict__ Rb,
    const float* __restrict__ W1, const float* __restrict__ b1,
    const float* __restrict__ W2, const float* __restrict__ b2,
    float* __restrict__ Zout, float* __restrict__ out_main)
{
  __shared__ float KsT[DD][CLEN + 2];   // 33792 B
  __shared__ float Qs[8][132];          //  4224 B
  __shared__ float sc[8][CLEN + 2];     //  2112 B
  __shared__ float zeff[DD];
  __shared__ float den[8];
  __shared__ float Ao[8][132];          //  4224 B
  __shared__ float H1[8][132];          //  4224 B
  int c = blockIdx.y, b = blockIdx.z, tid = threadIdx.x;
  const float* Kc = Kb + (b * TT + c * CLEN) * DD;
  const float* Vc = Vb + (b * TT + c * CLEN) * DD;
  int sub = blockIdx.x;
  int t0 = sub * 8;
  int tlim = t0 + 8;
  const float* Qc = Qb + (b * TT + c * CLEN) * DD;
  for (int idx = tid; idx < tlim * 32; idx += 256) {
    int t = idx >> 5, c4 = (idx & 31) * 4;
    float4 vv = *(const float4*)&Kc[t * DD + c4];
    KsT[c4 + 0][t] = vv.x; KsT[c4 + 1][t] = vv.y;
    KsT[c4 + 2][t] = vv.z; KsT[c4 + 3][t] = vv.w;
  }
  {
    int r = tid >> 5, c4 = (tid & 31) * 4;
    *(float4*)&Qs[r][c4] = *(const float4*)&Qc[(t0 + r) * DD + c4];
  }
  if (tid < DD) zeff[tid] = prefz[(b * NCH + c) * DD + tid];
  __syncthreads();
  // scores
  {
    int tm = tid >> 5, tn = tid & 31;
    int tau0 = tn * 2;
    if (tau0 < tlim) {
      float s0 = 0.f, s1 = 0.f;
#pragma unroll 8
      for (int k = 0; k < DD; k++) {
        float q = Qs[tm][k];
        float2 kk = *(const float2*)&KsT[k][tau0];
        s0 += q * kk.x;
        s1 += q * kk.y;
      }
      int t = t0 + tm;
      sc[tm][tau0]     = (tau0     <= t) ? s0 : 0.f;
      sc[tm][tau0 + 1] = (tau0 + 1 <= t) ? s1 : 0.f;
    }
  }
  __syncthreads();
  // den: 32 lanes per row, shuffle-reduce
  {
    int r = tid >> 5, g = tid & 31;
    int t = t0 + r;
    float p = 0.f;
    for (int tau = g; tau <= t; tau += 32) p += sc[r][tau];
#pragma unroll 4
    for (int k = g; k < DD; k += 32) p += Qs[r][k] * zeff[k];
#pragma unroll
    for (int off = 1; off < 32; off <<= 1) p += __shfl_xor(p, off);
    if (g == 0) den[r] = p + 1e-5f;
  }
  __syncthreads();
  // numerator -> Ao (LDS)
  int tl = tid & 31, r = tid >> 5;
  int l0 = tl * 4;
  {
    float n0[4] = {};
#pragma unroll 4
    for (int tau = 0; tau < tlim; tau++) {
      float4 v4 = *(const float4*)&Vc[tau * DD + l0];
      float s = sc[r][tau];
      n0[0] += s * v4.x; n0[1] += s * v4.y; n0[2] += s * v4.z; n0[3] += s * v4.w;
    }
    const float* P = prefS + (size_t)(b * NCH + c) * DD * DD;
#pragma unroll 4
    for (int i = 0; i < DD; i++) {
      float4 p4 = *(const float4*)&P[i * DD + l0];
      float q = Qs[r][i];
      n0[0] += q * p4.x; n0[1] += q * p4.y; n0[2] += q * p4.z; n0[3] += q * p4.w;
    }
    float dd = den[r];
    *(float4*)&Ao[r][l0] = make_float4(n0[0] / dd, n0[1] / dd, n0[2] / dd, n0[3] / dd);
  }
  // Z output: sub==7 has full K staged
  if (sub == 7 && tid < DD) {
    int i = tid;
    float a = zeff[i];
    for (int t = 0; t < CLEN; t++) {
      a += KsT[i][t];
      a = fminf(fmaxf(a, -CLAMPV), CLAMPV);
      __builtin_nontemporal_store(a, &Zout[(size_t)(b * TT + c * CLEN + t) * DD + i]);
    }
  }
  __syncthreads();
  // FFN layer 1
  {
    float a1[4] = {};
#pragma unroll 8
    for (int k = 0; k < DD; k++) {
      float4 w = *(const float4*)&W1[k * DD + l0];
      float a = Ao[r][k];
      a1[0] += a * w.x; a1[1] += a * w.y; a1[2] += a * w.z; a1[3] += a * w.w;
    }
    float4 bv = *(const float4*)&b1[l0];
    float4 h;
    h.x = fmaxf(a1[0] + bv.x, 0.f);
    h.y = fmaxf(a1[1] + bv.y, 0.f);
    h.z = fmaxf(a1[2] + bv.z, 0.f);
    h.w = fmaxf(a1[3] + bv.w, 0.f);
    *(float4*)&H1[r][l0] = h;
  }
  __syncthreads();
  // FFN layer 2 + residual
  {
    float a2[4] = {};
#pragma unroll 8
    for (int k = 0; k < DD; k++) {
      float4 w = *(const float4*)&W2[k * DD + l0];
      float a = H1[r][k];
      a2[0] += a * w.x; a2[1] += a * w.y; a2[2] += a * w.z; a2[3] += a * w.w;
    }
    int grow = b * TT + c * CLEN + t0 + r;
    float4 b2v = *(const float4*)&b2[l0];
    float4 rv = *(const float4*)&Rb[grow * DD + l0];
    float4 o;
    o.x = fmaxf(a2[0] + b2v.x, 0.f) + rv.x;
    o.y = fmaxf(a2[1] + b2v.y, 0.f) + rv.y;
    o.z = fmaxf(a2[2] + b2v.z, 0.f) + rv.z;
    o.w = fmaxf(a2[3] + b2v.w, 0.f) + rv.w;
    *(float4*)&out_main[grow * DD + l0] = o;
  }
}

extern "C" void kernel_launch(void* const* d_in, const int* in_sizes, int n_in,
                              void* d_out, int out_size, void* d_ws, size_t ws_size,
                              hipStream_t stream)
{
  const float* x     = (const float*)d_in[0];
  const float* S0    = (const float*)d_in[1];
  const float* Z0    = (const float*)d_in[2];
  const float* gamma = (const float*)d_in[3];
  const float* beta  = (const float*)d_in[4];
  const float* Wk    = (const float*)d_in[5];
  const float* Wq    = (const float*)d_in[6];
  const float* Wv    = (const float*)d_in[7];
  const float* W1    = (const float*)d_in[8];
  const float* b1    = (const float*)d_in[9];
  const float* W2    = (const float*)d_in[10];
  const float* b2    = (const float*)d_in[11];
  const float* Ws    = (const float*)d_in[12];
  const float* bs    = (const float*)d_in[13];

  float* out_main = (float*)d_out;                       // [B,T,D]
  float* Sout = out_main + NROW * DD;                    // [B,T,D*D]
  float* Zout = Sout + (size_t)NROW * DD * DD;           // [B,T,D]

  float* ws_f   = (float*)d_ws;
  float* Kb     = ws_f;                  // 524288
  float* Qb     = Kb + 524288;           // 524288
  float* Vb     = Qb + 524288;           // 524288
  float* Rb     = Vb + 524288;           // 524288  (xn@Ws + bs)
  float* prefS  = Rb + 524288;           // 1048576 (exclusive prefix + S0)
  float* prefz  = prefS + 1048576;       // 8192    (exclusive prefix + Z0)

  gemm_qkvs<<<dim3(8, 64), 256, 0, stream>>>(x, gamma, beta, Wk, Wq, Wv, Ws, bs,
                                             Kb, Qb, Vb, Rb);
  prefix_kernel<<<dim3(2, 16, BB), 256, 0, stream>>>(Kb, Vb, S0, Z0, prefS, prefz, Sout);
  attn_kernel<<<dim3(8, NCH, BB), 256, 0, stream>>>(Kb, Qb, Vb, prefS, prefz, Rb,
                                                    W1, b1, W2, b2, Zout, out_main);
}